// Round 7
// baseline (9065.429 us; speedup 1.0000x reference)
//
#include <hip/hip_runtime.h>
#include <hip/hip_bf16.h>
#include <cstddef>

// ---------------- problem constants ----------------
#define BB    32
#define T1    129
#define TT    128
#define SS    256
#define EE    512
#define HH    1024
#define KK    128
#define VV    128
#define VOC   8000
#define VOCP  8064
#define KLOG  1152          // H + V
#define NB2   128           // persistent grid
#define NATT  32

typedef __bf16 bf16x8 __attribute__((ext_vector_type(8)));
typedef float  f32x4  __attribute__((ext_vector_type(4)));
typedef unsigned int u32x4 __attribute__((ext_vector_type(4)));

#define MFMA(a,b,c) __builtin_amdgcn_mfma_f32_16x16x32_bf16((a),(b),(c),0,0,0)
#define VMCNT0 do { asm volatile("s_waitcnt vmcnt(0)" ::: "memory"); \
                    __builtin_amdgcn_sched_barrier(0); } while (0)

// Coherent (cross-XCD) primitives: read/write through the memory-side cache,
// bypassing the non-coherent per-XCD L2s.
__device__ __forceinline__ void cload_b8(bf16x8& d, const __hip_bfloat16* p) {
    asm volatile("global_load_dwordx4 %0, %1, off sc0 sc1" : "=v"(d) : "v"(p));
}
__device__ __forceinline__ void cload_f4(f32x4& d, const float* p) {
    asm volatile("global_load_dwordx4 %0, %1, off sc0 sc1" : "=v"(d) : "v"(p));
}
__device__ __forceinline__ int coh_load_i32(const int* p) {
    int r;
    asm volatile("global_load_dword %0, %1, off sc0 sc1\n\ts_waitcnt vmcnt(0)"
                 : "=v"(r) : "v"(p) : "memory");
    return r;
}
__device__ __forceinline__ void cstore16(const void* p, u32x4 v) {
    asm volatile("global_store_dwordx4 %0, %1, off sc0 sc1" :: "v"(p), "v"(v) : "memory");
}

union bf8u { __hip_bfloat16 h[8]; bf16x8 v; };

__device__ __forceinline__ bf16x8 cvt8(float4 a, float4 b) {
    bf8u u;
    u.h[0] = __float2bfloat16(a.x); u.h[1] = __float2bfloat16(a.y);
    u.h[2] = __float2bfloat16(a.z); u.h[3] = __float2bfloat16(a.w);
    u.h[4] = __float2bfloat16(b.x); u.h[5] = __float2bfloat16(b.y);
    u.h[6] = __float2bfloat16(b.z); u.h[7] = __float2bfloat16(b.w);
    return u.v;
}
__device__ __forceinline__ float bfu(unsigned short u) {
    return __uint_as_float(((unsigned)u) << 16);
}
__device__ __forceinline__ float fsig(float x)  { return 1.f / (1.f + __expf(-x)); }

// ---------------- fence-free grid barrier (128 leaves: 16 groups x 8) ------
__device__ __forceinline__ void grid_barrier(int* bar, int bid, int& gen)
{
    asm volatile("s_waitcnt vmcnt(0)" ::: "memory");   // drain my coherent stores
    __syncthreads();
    if (threadIdx.x == 0) {
        int target = gen + 1;
        int prev = __hip_atomic_fetch_add(&bar[(bid >> 3) * 32], 1,
                                          __ATOMIC_RELAXED, __HIP_MEMORY_SCOPE_AGENT);
        if (((prev + 1) & 7) == 0) {
            int pr = __hip_atomic_fetch_add(&bar[640], 1,
                                            __ATOMIC_RELAXED, __HIP_MEMORY_SCOPE_AGENT);
            if (((pr + 1) & 15) == 0)
                __hip_atomic_fetch_add(&bar[768], 1,
                                       __ATOMIC_RELAXED, __HIP_MEMORY_SCOPE_AGENT);
        }
        while (coh_load_i32(&bar[768]) < target)
            __builtin_amdgcn_s_sleep(2);
        gen = target;
    }
    __syncthreads();
}

// ---------------- prologue kernels ----------------
__global__ void pack_wout(const float* __restrict__ W, __hip_bfloat16* __restrict__ Wp)
{
    int v = blockIdx.y;
    int k = blockIdx.x * 256 + threadIdx.x;
    if (k >= KLOG) return;
    float w = (v < VOC) ? W[(size_t)v * KLOG + k] : 0.f;
    Wp[(size_t)v * KLOG + k] = __float2bfloat16(w);
}

// packed emb-weight: Wp1e[rp][k], rp = 4*j + g, orig row = g*H + j; k<512
__global__ void pack_w1emb(const float* __restrict__ Wih1, __hip_bfloat16* __restrict__ Wp)
{
    int rp = blockIdx.y;
    int k  = blockIdx.x * 256 + threadIdx.x;
    if (k >= EE) return;
    int orow = (rp & 3) * HH + (rp >> 2);
    Wp[(size_t)rp * EE + k] = __float2bfloat16(Wih1[(size_t)orow * (EE + VV) + k]);
}

__global__ void init_state(const float* __restrict__ enc,
                           __hip_bfloat16* __restrict__ H1,
                           __hip_bfloat16* __restrict__ H2,
                           __hip_bfloat16* __restrict__ CTX,
                           int* __restrict__ bar)
{
    int i = blockIdx.x * 256 + threadIdx.x;
    if (i < 1024) bar[i] = 0;
    if (i < BB * VV) CTX[i] = __float2bfloat16(0.f);
    if (i >= BB * HH) return;
    __hip_bfloat16 eb = __float2bfloat16(enc[i]);
    H1[i] = eb;   // h1(-1) = encoder_hidden
    H2[i] = eb;   // h2(-1) = encoder_hidden
}

__global__ void gather_emb(const int* __restrict__ tok, const float* __restrict__ emb,
                           __hip_bfloat16* __restrict__ Aemb)
{
    int bid = blockIdx.x;          // t*32 + b
    int t = bid >> 5, b = bid & 31;
    int id = tok[b * T1 + t];
    const float* er = emb + (size_t)id * EE;
    __hip_bfloat16* dst = Aemb + (size_t)bid * EE;
    for (int k = threadIdx.x; k < EE; k += 256)
        dst[k] = __float2bfloat16(er[k]);
}

// ---------------- G1emb = Aemb[4096x512] @ Wp1e^T[512x4096] (bf16 out) -----
__global__ __launch_bounds__(256) void g1emb_gemm(
    const __hip_bfloat16* __restrict__ A,
    const __hip_bfloat16* __restrict__ W,
    __hip_bfloat16* __restrict__ C)
{
    int n0 = blockIdx.x * 128;
    int m0 = blockIdx.y * 128;
    int wv = threadIdx.x >> 6, l = threadIdx.x & 63;
    int l15 = l & 15, l4 = l >> 4;

    f32x4 acc[8][2] = {};
    const __hip_bfloat16* Ap = A + (size_t)(m0 + l15) * EE + l4 * 8;
    const __hip_bfloat16* Bp = W + (size_t)(n0 + wv * 32 + l15) * EE + l4 * 8;

    for (int kt = 0; kt < EE; kt += 32) {
        bf16x8 b0 = *(const bf16x8*)(Bp + kt);
        bf16x8 b1 = *(const bf16x8*)(Bp + (size_t)16 * EE + kt);
        #pragma unroll
        for (int ms = 0; ms < 8; ++ms) {
            bf16x8 a = *(const bf16x8*)(Ap + (size_t)ms * 16 * EE + kt);
            acc[ms][0] = MFMA(a, b0, acc[ms][0]);
            acc[ms][1] = MFMA(a, b1, acc[ms][1]);
        }
    }
    #pragma unroll
    for (int ms = 0; ms < 8; ++ms)
        #pragma unroll
        for (int ns = 0; ns < 2; ++ns) {
            int col = n0 + wv * 32 + ns * 16 + l15;
            #pragma unroll
            for (int r = 0; r < 4; ++r) {
                int m = m0 + ms * 16 + l4 * 4 + r;
                C[(size_t)m * 4096 + col] = __float2bfloat16(acc[ms][ns][r]);
            }
        }
}

// ---------------- persistent decoder ----------------
// 128 blocks x 512 threads. 8 waves = (cg in 0..1) x (kq in 0..3).
// Block owns 32 packed gate-cols = 8 hidden units.
__global__ __launch_bounds__(512, 2) void decoder_persistent(
    const float* __restrict__ Wih1, const float* __restrict__ Whh1, const float* __restrict__ b1v,
    const float* __restrict__ Wih2, const float* __restrict__ Whh2, const float* __restrict__ b2v,
    const float* __restrict__ Wq,   const float* __restrict__ bq,
    const float* __restrict__ keys, const float* __restrict__ vals,
    const __hip_bfloat16* __restrict__ G1,
    __hip_bfloat16* H1, __hip_bfloat16* H2, __hip_bfloat16* CTX,
    float* h2f, __hip_bfloat16* Alog, int* bar)
{
    const int bid = blockIdx.x;
    const int tid = threadIdx.x;
    const int w   = tid >> 6;
    const int cg  = w >> 2;
    const int kq  = w & 3;
    const int l   = tid & 63;
    const int l15 = l & 15, l4 = l >> 4;
    const int n0  = bid * 32 + cg * 16;

    __shared__ float G[2][4][32][17];                 // [cg][kq][batch][col]
    __shared__ alignas(16) __hip_bfloat16 hstage[32][8];
    __shared__ alignas(16) float hstagef[32][8];
    __shared__ alignas(16) __hip_bfloat16 cstage[128];
    __shared__ alignas(16) float hs[HH];
    __shared__ float qs[KK];
    __shared__ float es[SS];
    __shared__ float red[512];

    // ---- weight fragments (no emb weights needed: G1emb precomputed) ----
    bf16x8 w1c, w1h[8], w2a[8], w2b[8];
    {
        const int col  = n0 + l15;
        const int orow = (col & 3) * HH + (col >> 2);
        {
            int k0 = kq * 32 + l4 * 8;
            const float* s = Wih1 + (size_t)orow * (EE + VV) + EE + k0;
            w1c = cvt8(*(const float4*)s, *(const float4*)(s + 4));
        }
        #pragma unroll
        for (int s = 0; s < 8; ++s) {
            int k0 = kq * 256 + s * 32 + l4 * 8;
            const float* p1 = Whh1 + (size_t)orow * HH + k0;
            const float* p2 = Wih2 + (size_t)orow * HH + k0;
            const float* p3 = Whh2 + (size_t)orow * HH + k0;
            w1h[s] = cvt8(*(const float4*)p1, *(const float4*)(p1 + 4));
            w2a[s] = cvt8(*(const float4*)p2, *(const float4*)(p2 + 4));
            w2b[s] = cvt8(*(const float4*)p3, *(const float4*)(p3 + 4));
        }
    }

    // ---- cell-thread state (tid<256: b = tid>>3, jl = tid&7) ----
    float c1r = 0.f, c2r = 0.f;
    float gb1[4], gb2[4];
    {
        int jl = tid & 7;
        int j  = bid * 8 + jl;
        #pragma unroll
        for (int g = 0; g < 4; ++g) { gb1[g] = b1v[g * HH + j]; gb2[g] = b2v[g * HH + j]; }
    }

    // ---- pre-acc prologue: acc1 = Whh1*h1(-1), acc2 = Whh2*h2(-1) (normal loads) ----
    f32x4 acc1A = {0,0,0,0}, acc1B = {0,0,0,0}, acc2A = {0,0,0,0}, acc2B = {0,0,0,0};
    #pragma unroll
    for (int s = 0; s < 8; ++s) {
        int k0 = kq * 256 + s * 32 + l4 * 8;
        bf16x8 a0 = *(const bf16x8*)(H1 + (size_t)l15 * HH + k0);
        bf16x8 a1 = *(const bf16x8*)(H1 + (size_t)(16 + l15) * HH + k0);
        acc1A = MFMA(a0, w1h[s], acc1A);
        acc1B = MFMA(a1, w1h[s], acc1B);
        bf16x8 b0 = *(const bf16x8*)(H2 + (size_t)l15 * HH + k0);
        bf16x8 b1 = *(const bf16x8*)(H2 + (size_t)(16 + l15) * HH + k0);
        acc2A = MFMA(b0, w2b[s], acc2A);
        acc2B = MFMA(b1, w2b[s], acc2B);
    }

    int gen = 0;
    // RACE FIX (round 7): S1 of t=0 overwrites H1 in place. Without a grid
    // barrier here, a fast block can store h1(0) into H1 while a slow block
    // is still reading h1(-1) for its prologue pre-accumulation (cross-block
    // WAR). One barrier makes all prologue reads happen-before any S1 write.
    grid_barrier(bar, bid, gen);

    bf16x8 fA[8], fB[8];

    #pragma unroll 1
    for (int t = 0; t < TT; ++t) {
        __hip_bfloat16* AlogT = Alog + (size_t)t * BB * KLOG;

        // ======== S1: + Wctx*ctx(t-1), cell1 -> h1(t) ========
        if (t > 0) {
            int k0 = kq * 32 + l4 * 8;
            cload_b8(fA[0], CTX + (size_t)l15 * VV + k0);
            cload_b8(fB[0], CTX + (size_t)(16 + l15) * VV + k0);
            VMCNT0;
            acc1A = MFMA(fA[0], w1c, acc1A);
            acc1B = MFMA(fB[0], w1c, acc1B);
        }
        #pragma unroll
        for (int r = 0; r < 4; ++r) {
            G[cg][kq][l4 * 4 + r][l15]      = acc1A[r];
            G[cg][kq][16 + l4 * 4 + r][l15] = acc1B[r];
        }
        acc1A = (f32x4){0,0,0,0}; acc1B = (f32x4){0,0,0,0};
        __syncthreads();
        if (tid < 256) {
            int b = tid >> 3, jl = tid & 7;
            int cg2 = jl >> 2, cb = (jl & 3) * 4;
            const __hip_bfloat16* gp = G1 + ((size_t)(t * 32 + b)) * 4096 + bid * 32 + jl * 4;
            ushort4 gu = *(const ushort4*)gp;
            float g0 = G[cg2][0][b][cb+0] + G[cg2][1][b][cb+0] + G[cg2][2][b][cb+0] + G[cg2][3][b][cb+0] + bfu(gu.x) + gb1[0];
            float g1 = G[cg2][0][b][cb+1] + G[cg2][1][b][cb+1] + G[cg2][2][b][cb+1] + G[cg2][3][b][cb+1] + bfu(gu.y) + gb1[1];
            float g2 = G[cg2][0][b][cb+2] + G[cg2][1][b][cb+2] + G[cg2][2][b][cb+2] + G[cg2][3][b][cb+2] + bfu(gu.z) + gb1[2];
            float g3 = G[cg2][0][b][cb+3] + G[cg2][1][b][cb+3] + G[cg2][2][b][cb+3] + G[cg2][3][b][cb+3] + bfu(gu.w) + gb1[3];
            c1r = fsig(g1) * c1r + fsig(g0) * tanhf(g2);
            float h = fsig(g3) * tanhf(c1r);
            hstage[b][jl] = __float2bfloat16(h);
        }
        __syncthreads();
        if (tid < 32)
            cstore16(H1 + (size_t)tid * HH + bid * 8, *(const u32x4*)&hstage[tid][0]);
        grid_barrier(bar, bid, gen);

        // ======== S2: gates2 += Wih2*h1(t); pre-acc gates1(t+1) += Whh1*h1(t) ========
        #pragma unroll
        for (int s = 0; s < 8; ++s) {
            int k0 = kq * 256 + s * 32 + l4 * 8;
            cload_b8(fA[s], H1 + (size_t)l15 * HH + k0);
            cload_b8(fB[s], H1 + (size_t)(16 + l15) * HH + k0);
        }
        VMCNT0;
        #pragma unroll
        for (int s = 0; s < 8; ++s) {
            acc2A = MFMA(fA[s], w2a[s], acc2A);
            acc2B = MFMA(fB[s], w2a[s], acc2B);
            acc1A = MFMA(fA[s], w1h[s], acc1A);
            acc1B = MFMA(fB[s], w1h[s], acc1B);
        }
        #pragma unroll
        for (int r = 0; r < 4; ++r) {
            G[cg][kq][l4 * 4 + r][l15]      = acc2A[r];
            G[cg][kq][16 + l4 * 4 + r][l15] = acc2B[r];
        }
        acc2A = (f32x4){0,0,0,0}; acc2B = (f32x4){0,0,0,0};
        __syncthreads();
        if (tid < 256) {
            int b = tid >> 3, jl = tid & 7;
            int cg2 = jl >> 2, cb = (jl & 3) * 4;
            float g0 = G[cg2][0][b][cb+0] + G[cg2][1][b][cb+0] + G[cg2][2][b][cb+0] + G[cg2][3][b][cb+0] + gb2[0];
            float g1 = G[cg2][0][b][cb+1] + G[cg2][1][b][cb+1] + G[cg2][2][b][cb+1] + G[cg2][3][b][cb+1] + gb2[1];
            float g2 = G[cg2][0][b][cb+2] + G[cg2][1][b][cb+2] + G[cg2][2][b][cb+2] + G[cg2][3][b][cb+2] + gb2[2];
            float g3 = G[cg2][0][b][cb+3] + G[cg2][1][b][cb+3] + G[cg2][2][b][cb+3] + G[cg2][3][b][cb+3] + gb2[3];
            c2r = fsig(g1) * c2r + fsig(g0) * tanhf(g2);
            float h = fsig(g3) * tanhf(c2r);
            hstage[b][jl]  = __float2bfloat16(h);
            hstagef[b][jl] = h;
        }
        __syncthreads();
        if (tid < 32) {
            u32x4 v = *(const u32x4*)&hstage[tid][0];
            cstore16(H2 + (size_t)tid * HH + bid * 8, v);
            *(u32x4*)(AlogT + (size_t)tid * KLOG + bid * 8) = v;   // normal store
            cstore16(h2f + (size_t)tid * HH + bid * 8,     *(const u32x4*)&hstagef[tid][0]);
            cstore16(h2f + (size_t)tid * HH + bid * 8 + 4, *(const u32x4*)&hstagef[tid][4]);
        }
        grid_barrier(bar, bid, gen);

        // ======== S3: pre-acc gates2(t+1) += Whh2*h2(t);  attn on blocks 0..31 ========
        #pragma unroll
        for (int s = 0; s < 8; ++s) {
            int k0 = kq * 256 + s * 32 + l4 * 8;
            cload_b8(fA[s], H2 + (size_t)l15 * HH + k0);
            cload_b8(fB[s], H2 + (size_t)(16 + l15) * HH + k0);
        }
        VMCNT0;
        #pragma unroll
        for (int s = 0; s < 8; ++s) {
            acc2A = MFMA(fA[s], w2b[s], acc2A);
            acc2B = MFMA(fB[s], w2b[s], acc2B);
        }

        if (bid < NATT) {
            const int b = bid;
            if (tid < 256) {            // stage h2(t) fp32 -> LDS (coherent)
                f32x4 hv;
                cload_f4(hv, h2f + (size_t)b * HH + tid * 4);
                VMCNT0;
                *(f32x4*)&hs[tid * 4] = hv;
            }
            __syncthreads();
            {   // q[k'] = Wq[k',:] . h2 + bq   (4 threads per k', fp32)
                int kp = tid >> 2, qc = tid & 3;
                const float4* wr = (const float4*)(Wq + (size_t)kp * HH + qc * 256);
                const float* hh = hs + qc * 256;
                float acc = 0.f;
                #pragma unroll 4
                for (int c = 0; c < 64; ++c) {
                    float4 wv4 = wr[c];
                    acc += wv4.x*hh[c*4] + wv4.y*hh[c*4+1] + wv4.z*hh[c*4+2] + wv4.w*hh[c*4+3];
                }
                red[tid] = acc;
            }
            __syncthreads();
            if (tid < KK) qs[tid] = red[tid*4] + red[tid*4+1] + red[tid*4+2] + red[tid*4+3] + bq[tid];
            __syncthreads();
            {   // energy[s] = keys[b,s,:] . q   (2 threads per s)
                int s = tid >> 1, hf = tid & 1;
                const float4* kr = (const float4*)(keys + ((size_t)b * SS + s) * KK + hf * 64);
                const float* qh = qs + hf * 64;
                float acc = 0.f;
                #pragma unroll
                for (int k4 = 0; k4 < 16; ++k4) {
                    float4 kv = kr[k4];
                    acc += kv.x*qh[k4*4] + kv.y*qh[k4*4+1] + kv.z*qh[k4*4+2] + kv.w*qh[k4*4+3];
                }
                red[tid] = acc;
            }
            __syncthreads();
            if (tid < SS) es[tid] = red[tid*2] + red[tid*2+1];
            __syncthreads();
            if (tid < SS) red[tid] = es[tid];
            __syncthreads();
            for (int off = 128; off > 0; off >>= 1) {
                if (tid < off) red[tid] = fmaxf(red[tid], red[tid + off]);
                __syncthreads();
            }
            float mx = red[0];
            __syncthreads();
            if (tid < SS) { float ev = __expf(es[tid] - mx); es[tid] = ev; red[tid] = ev; }
            __syncthreads();
            for (int off = 128; off > 0; off >>= 1) {
                if (tid < off) red[tid] += red[tid + off];
                __syncthreads();
            }
            float inv = 1.f / red[0];
            __syncthreads();
            {   // ctx[v] = sum_s es[s]*vals[b,s,v]  (4 threads per v, s-quarters)
                int v = tid & 127, sh = tid >> 7;
                const float* vb = vals + ((size_t)b * SS + sh * 64) * VV + v;
                float acc = 0.f;
                for (int i = 0; i < 64; ++i) acc += es[sh * 64 + i] * vb[(size_t)i * VV];
                red[tid] = acc;
            }
            __syncthreads();
            if (tid < VV) {
                float cv = (red[tid] + red[tid+128] + red[tid+256] + red[tid+384]) * inv;
                cstage[tid] = __float2bfloat16(cv);
            }
            __syncthreads();
            if (tid < 16) {
                u32x4 v = *(const u32x4*)&cstage[tid * 8];
                cstore16(CTX + (size_t)b * VV + tid * 8, v);
                *(u32x4*)(AlogT + (size_t)b * KLOG + HH + tid * 8) = v;  // normal store
            }
        }
        grid_barrier(bar, bid, gen);
    }
}

// ---------------- deferred logits GEMM ----------------
__global__ __launch_bounds__(256) void logits_gemm(
    const __hip_bfloat16* __restrict__ Alog,
    const __hip_bfloat16* __restrict__ W,
    const float* __restrict__ bout,
    float* __restrict__ out)
{
    int n0 = blockIdx.x * 128;
    int m0 = blockIdx.y * 128;
    int wv = threadIdx.x >> 6, l = threadIdx.x & 63;
    int l15 = l & 15, l4 = l >> 4;

    f32x4 acc[8][2] = {};
    const __hip_bfloat16* Ap = Alog + (size_t)(m0 + l15) * KLOG + l4 * 8;
    const __hip_bfloat16* Bp = W    + (size_t)(n0 + wv * 32 + l15) * KLOG + l4 * 8;

    for (int kt = 0; kt < KLOG; kt += 32) {
        bf16x8 b0 = *(const bf16x8*)(Bp + kt);
        bf16x8 b1 = *(const bf16x8*)(Bp + (size_t)16 * KLOG + kt);
        #pragma unroll
        for (int ms = 0; ms < 8; ++ms) {
            bf16x8 a = *(const bf16x8*)(Ap + (size_t)ms * 16 * KLOG + kt);
            acc[ms][0] = MFMA(a, b0, acc[ms][0]);
            acc[ms][1] = MFMA(a, b1, acc[ms][1]);
        }
    }
    #pragma unroll
    for (int ms = 0; ms < 8; ++ms)
        #pragma unroll
        for (int ns = 0; ns < 2; ++ns) {
            int col = n0 + wv * 32 + ns * 16 + l15;
            if (col < VOC) {
                float bias = bout[col];
                #pragma unroll
                for (int r = 0; r < 4; ++r) {
                    int m = m0 + ms * 16 + l4 * 4 + r;
                    int b = m & 31, t = m >> 5;
                    out[((size_t)b * TT + t) * VOC + col] = acc[ms][ns][r] + bias;
                }
            }
        }
}

// ---------------- host ----------------
extern "C" void kernel_launch(void* const* d_in, const int* in_sizes, int n_in,
                              void* d_out, int out_size, void* d_ws, size_t ws_size,
                              hipStream_t stream)
{
    (void)in_sizes; (void)n_in; (void)out_size; (void)ws_size;
    const int*   dec  = (const int*)  d_in[0];
    const float* enc  = (const float*)d_in[2];
    const float* keys = (const float*)d_in[3];
    const float* vals = (const float*)d_in[4];
    const float* emb  = (const float*)d_in[5];
    const float* Wih1 = (const float*)d_in[6];
    const float* Whh1 = (const float*)d_in[7];
    const float* b1   = (const float*)d_in[8];
    const float* Wih2 = (const float*)d_in[9];
    const float* Whh2 = (const float*)d_in[10];
    const float* b2   = (const float*)d_in[11];
    const float* Wq   = (const float*)d_in[12];
    const float* bq   = (const float*)d_in[13];
    const float* Wout = (const float*)d_in[14];
    const float* bout = (const float*)d_in[15];
    float* out = (float*)d_out;

    // workspace carve (~60 MB). Aemb/Wp1e alias the Alog region: they are
    // consumed by g1emb_gemm strictly before the decoder writes Alog.
    char* p = (char*)d_ws;
    __hip_bfloat16* WoutP = (__hip_bfloat16*)p; p += (size_t)VOCP * KLOG * 2;        // 18.6 MB
    __hip_bfloat16* G1    = (__hip_bfloat16*)p; p += (size_t)TT * BB * 4 * HH * 2;   // 32 MB
    __hip_bfloat16* Alog  = (__hip_bfloat16*)p; p += (size_t)TT * BB * KLOG * 2;     // 9.4 MB
    __hip_bfloat16* H1    = (__hip_bfloat16*)p; p += (size_t)BB * HH * 2;            // 64 KB
    __hip_bfloat16* H2    = (__hip_bfloat16*)p; p += (size_t)BB * HH * 2;            // 64 KB
    __hip_bfloat16* CTX   = (__hip_bfloat16*)p; p += (size_t)BB * VV * 2;            // 8 KB
    float* h2f = (float*)p; p += (size_t)BB * HH * 4;                                // 128 KB
    int* bar = (int*)p; p += 4096;
    __hip_bfloat16* Aemb  = Alog;                                  // 4 MB   (alias)
    __hip_bfloat16* Wp1e  = Alog + (size_t)TT * BB * EE;           // 4 MB   (alias)

    pack_wout  <<<dim3((KLOG + 255) / 256, VOCP), 256, 0, stream>>>(Wout, WoutP);
    pack_w1emb <<<dim3(2, 4 * HH), 256, 0, stream>>>(Wih1, Wp1e);
    init_state <<<dim3(128), 256, 0, stream>>>(enc, H1, H2, CTX, bar);
    gather_emb <<<dim3(TT * BB), 256, 0, stream>>>(dec, emb, Aemb);
    g1emb_gemm <<<dim3(32, 32), 256, 0, stream>>>(Aemb, Wp1e, G1);

    decoder_persistent<<<dim3(NB2), 512, 0, stream>>>(
        Wih1, Whh1, b1, Wih2, Whh2, b2, Wq, bq, keys, vals,
        G1, H1, H2, CTX, h2f, Alog, bar);

    logits_gemm<<<dim3(VOCP / 128, (BB * TT) / 128), 256, 0, stream>>>(Alog, WoutP, bout, out);
}

// Round 8
// 7833.949 us; speedup vs baseline: 1.1572x; 1.1572x over previous
//
#include <hip/hip_runtime.h>
#include <hip/hip_bf16.h>
#include <cstddef>

// ---------------- problem constants ----------------
#define BB    32
#define T1    129
#define TT    128
#define SS    256
#define EE    512
#define HH    1024
#define KK    128
#define VV    128
#define VOC   8000
#define VOCP  8064
#define KLOG  1152          // H + V
#define NB2   128           // persistent grid
#define NATT  32

typedef __bf16 bf16x8 __attribute__((ext_vector_type(8)));
typedef float  f32x4  __attribute__((ext_vector_type(4)));
typedef unsigned int u32x4 __attribute__((ext_vector_type(4)));

#define MFMA(a,b,c) __builtin_amdgcn_mfma_f32_16x16x32_bf16((a),(b),(c),0,0,0)
#define VMCNT0 do { asm volatile("s_waitcnt vmcnt(0)" ::: "memory"); \
                    __builtin_amdgcn_sched_barrier(0); } while (0)

// Coherent (cross-XCD) primitives. Writes go through to the memory-side
// cache (MALL); the matching reads are NORMAL cached loads of addresses that
// are single-use within the dispatch (step-indexed buffers), so the reader's
// L2 cannot hold a stale copy. Only h2f and the barrier word use coherent
// reads (tiny traffic).
__device__ __forceinline__ void cload_f4(f32x4& d, const float* p) {
    asm volatile("global_load_dwordx4 %0, %1, off sc0 sc1" : "=v"(d) : "v"(p));
}
__device__ __forceinline__ int coh_load_i32(const int* p) {
    int r;
    asm volatile("global_load_dword %0, %1, off sc0 sc1\n\ts_waitcnt vmcnt(0)"
                 : "=v"(r) : "v"(p) : "memory");
    return r;
}
__device__ __forceinline__ void cstore16(const void* p, u32x4 v) {
    asm volatile("global_store_dwordx4 %0, %1, off sc0 sc1" :: "v"(p), "v"(v) : "memory");
}

union bf8u { __hip_bfloat16 h[8]; bf16x8 v; };

__device__ __forceinline__ bf16x8 cvt8(float4 a, float4 b) {
    bf8u u;
    u.h[0] = __float2bfloat16(a.x); u.h[1] = __float2bfloat16(a.y);
    u.h[2] = __float2bfloat16(a.z); u.h[3] = __float2bfloat16(a.w);
    u.h[4] = __float2bfloat16(b.x); u.h[5] = __float2bfloat16(b.y);
    u.h[6] = __float2bfloat16(b.z); u.h[7] = __float2bfloat16(b.w);
    return u.v;
}
__device__ __forceinline__ float fsig(float x) { return 1.f / (1.f + __expf(-x)); }

// ---------------- fence-free grid barrier (128 leaves: 16 groups x 8) ------
__device__ __forceinline__ void grid_barrier(int* bar, int bid, int& gen)
{
    asm volatile("s_waitcnt vmcnt(0)" ::: "memory");   // drain my coherent stores
    __syncthreads();
    if (threadIdx.x == 0) {
        int target = gen + 1;
        int prev = __hip_atomic_fetch_add(&bar[(bid >> 3) * 32], 1,
                                          __ATOMIC_RELAXED, __HIP_MEMORY_SCOPE_AGENT);
        if (((prev + 1) & 7) == 0) {
            int pr = __hip_atomic_fetch_add(&bar[640], 1,
                                            __ATOMIC_RELAXED, __HIP_MEMORY_SCOPE_AGENT);
            if (((pr + 1) & 15) == 0)
                __hip_atomic_fetch_add(&bar[768], 1,
                                       __ATOMIC_RELAXED, __HIP_MEMORY_SCOPE_AGENT);
        }
        while (coh_load_i32(&bar[768]) < target)
            __builtin_amdgcn_s_sleep(2);
        gen = target;
    }
    __syncthreads();
    asm volatile("" ::: "memory");     // keep post-barrier loads below the barrier
}

// ---------------- prologue kernels ----------------
__global__ void pack_wout(const float* __restrict__ W, __hip_bfloat16* __restrict__ Wp)
{
    int v = blockIdx.y;
    int k = blockIdx.x * 256 + threadIdx.x;
    if (k >= KLOG) return;
    float w = (v < VOC) ? W[(size_t)v * KLOG + k] : 0.f;
    Wp[(size_t)v * KLOG + k] = __float2bfloat16(w);
}

__global__ void init_state(const float* __restrict__ enc,
                           __hip_bfloat16* __restrict__ H1s,
                           __hip_bfloat16* __restrict__ H2s,
                           int* __restrict__ bar)
{
    int i = blockIdx.x * 256 + threadIdx.x;
    if (i < 1024) bar[i] = 0;
    if (i >= BB * HH) return;
    __hip_bfloat16 eb = __float2bfloat16(enc[i]);
    H1s[i] = eb;   // slot 0 = h1(-1)
    H2s[i] = eb;   // slot 0 = h2(-1)
}

__global__ void gather_emb(const int* __restrict__ tok, const float* __restrict__ emb,
                           __hip_bfloat16* __restrict__ Aemb)
{
    int bid = blockIdx.x;          // t*32 + b
    int t = bid >> 5, b = bid & 31;
    int id = tok[b * T1 + t];
    const float* er = emb + (size_t)id * EE;
    __hip_bfloat16* dst = Aemb + (size_t)bid * EE;
    for (int k = threadIdx.x; k < EE; k += 256)
        dst[k] = __float2bfloat16(er[k]);
}

// ---------------- persistent decoder ----------------
// 128 blocks x 512 threads. 8 waves = (cg in 0..1) x (kq in 0..3).
// Block owns 32 packed gate-cols = 8 hidden units.
__global__ __launch_bounds__(512, 2) void decoder_persistent(
    const float* __restrict__ Wih1, const float* __restrict__ Whh1, const float* __restrict__ b1v,
    const float* __restrict__ Wih2, const float* __restrict__ Whh2, const float* __restrict__ b2v,
    const float* __restrict__ Wq,   const float* __restrict__ bq,
    const float* __restrict__ keys, const float* __restrict__ vals,
    const __hip_bfloat16* __restrict__ Aemb,
    __hip_bfloat16* H1s, __hip_bfloat16* H2s, __hip_bfloat16* CTXs,
    float* h2f, __hip_bfloat16* Alog, int* bar)
{
    const int bid = blockIdx.x;
    const int tid = threadIdx.x;
    const int w   = tid >> 6;
    const int cg  = w >> 2;
    const int kq  = w & 3;
    const int l   = tid & 63;
    const int l15 = l & 15, l4 = l >> 4;
    const int n0  = bid * 32 + cg * 16;

    __shared__ float G[2][4][32][17];                 // [cg][kq][batch][col]
    __shared__ alignas(16) __hip_bfloat16 hstage[32][8];
    __shared__ alignas(16) float hstagef[32][8];
    __shared__ alignas(16) __hip_bfloat16 cstage[128];
    __shared__ alignas(16) float hs[HH];
    __shared__ float qs[KK];
    __shared__ float es[SS];
    __shared__ float red[512];

    // ---- weight fragments in registers ----
    bf16x8 w1e[4], w1c, w1h[8], w2a[8], w2b[8];
    {
        const int col  = n0 + l15;
        const int orow = (col & 3) * HH + (col >> 2);   // packed rp=4j+g -> g*H+j
        #pragma unroll
        for (int s = 0; s < 4; ++s) {                   // emb section of W_ih1
            int k0 = kq * 128 + s * 32 + l4 * 8;
            const float* p0 = Wih1 + (size_t)orow * (EE + VV) + k0;
            w1e[s] = cvt8(*(const float4*)p0, *(const float4*)(p0 + 4));
        }
        {                                               // ctx section of W_ih1
            int k0 = kq * 32 + l4 * 8;
            const float* p0 = Wih1 + (size_t)orow * (EE + VV) + EE + k0;
            w1c = cvt8(*(const float4*)p0, *(const float4*)(p0 + 4));
        }
        #pragma unroll
        for (int s = 0; s < 8; ++s) {
            int k0 = kq * 256 + s * 32 + l4 * 8;
            const float* p1 = Whh1 + (size_t)orow * HH + k0;
            const float* p2 = Wih2 + (size_t)orow * HH + k0;
            const float* p3 = Whh2 + (size_t)orow * HH + k0;
            w1h[s] = cvt8(*(const float4*)p1, *(const float4*)(p1 + 4));
            w2a[s] = cvt8(*(const float4*)p2, *(const float4*)(p2 + 4));
            w2b[s] = cvt8(*(const float4*)p3, *(const float4*)(p3 + 4));
        }
    }

    // ---- cell-thread state (tid<256: b = tid>>3, jl = tid&7) ----
    float c1r = 0.f, c2r = 0.f;
    float gb1[4], gb2[4];
    {
        int jl = tid & 7;
        int j  = bid * 8 + jl;
        #pragma unroll
        for (int g = 0; g < 4; ++g) { gb1[g] = b1v[g * HH + j]; gb2[g] = b2v[g * HH + j]; }
    }

    // ---- prologue pre-acc (all normal loads; these slots are never overwritten):
    //      acc1 = Wemb*emb(0) + Whh1*h1(-1);  acc2 = Whh2*h2(-1)
    f32x4 acc1A = {0,0,0,0}, acc1B = {0,0,0,0}, acc2A = {0,0,0,0}, acc2B = {0,0,0,0};
    #pragma unroll
    for (int s = 0; s < 4; ++s) {
        int k0 = kq * 128 + s * 32 + l4 * 8;
        bf16x8 a0 = *(const bf16x8*)(Aemb + (size_t)l15 * EE + k0);
        bf16x8 a1 = *(const bf16x8*)(Aemb + (size_t)(16 + l15) * EE + k0);
        acc1A = MFMA(a0, w1e[s], acc1A);
        acc1B = MFMA(a1, w1e[s], acc1B);
    }
    #pragma unroll
    for (int s = 0; s < 8; ++s) {
        int k0 = kq * 256 + s * 32 + l4 * 8;
        bf16x8 a0 = *(const bf16x8*)(H1s + (size_t)l15 * HH + k0);
        bf16x8 a1 = *(const bf16x8*)(H1s + (size_t)(16 + l15) * HH + k0);
        acc1A = MFMA(a0, w1h[s], acc1A);
        acc1B = MFMA(a1, w1h[s], acc1B);
        bf16x8 b0 = *(const bf16x8*)(H2s + (size_t)l15 * HH + k0);
        bf16x8 b1 = *(const bf16x8*)(H2s + (size_t)(16 + l15) * HH + k0);
        acc2A = MFMA(b0, w2b[s], acc2A);
        acc2B = MFMA(b1, w2b[s], acc2B);
    }

    int gen = 0;
    bf16x8 fA[8], fB[8];

    #pragma unroll 1
    for (int t = 0; t < TT; ++t) {
        __hip_bfloat16* AlogT = Alog + (size_t)t * BB * KLOG;
        const __hip_bfloat16* H1t = H1s + (size_t)(t + 1) * BB * HH;   // h1(t) slot
        const __hip_bfloat16* H2t = H2s + (size_t)(t + 1) * BB * HH;   // h2(t) slot

        // ======== S1: + Wctx*ctx(t-1), cell1 -> h1(t) ========
        if (t > 0) {
            const __hip_bfloat16* Ct = CTXs + (size_t)t * BB * VV;     // ctx(t-1)
            int k0 = kq * 32 + l4 * 8;
            bf16x8 a0 = *(const bf16x8*)(Ct + (size_t)l15 * VV + k0);
            bf16x8 a1 = *(const bf16x8*)(Ct + (size_t)(16 + l15) * VV + k0);
            acc1A = MFMA(a0, w1c, acc1A);
            acc1B = MFMA(a1, w1c, acc1B);
        }
        #pragma unroll
        for (int r = 0; r < 4; ++r) {
            G[cg][kq][l4 * 4 + r][l15]      = acc1A[r];
            G[cg][kq][16 + l4 * 4 + r][l15] = acc1B[r];
        }
        acc1A = (f32x4){0,0,0,0}; acc1B = (f32x4){0,0,0,0};
        __syncthreads();
        if (tid < 256) {
            int b = tid >> 3, jl = tid & 7;
            int cg2 = jl >> 2, cb = (jl & 3) * 4;
            float g0 = G[cg2][0][b][cb+0] + G[cg2][1][b][cb+0] + G[cg2][2][b][cb+0] + G[cg2][3][b][cb+0] + gb1[0];
            float g1 = G[cg2][0][b][cb+1] + G[cg2][1][b][cb+1] + G[cg2][2][b][cb+1] + G[cg2][3][b][cb+1] + gb1[1];
            float g2 = G[cg2][0][b][cb+2] + G[cg2][1][b][cb+2] + G[cg2][2][b][cb+2] + G[cg2][3][b][cb+2] + gb1[2];
            float g3 = G[cg2][0][b][cb+3] + G[cg2][1][b][cb+3] + G[cg2][2][b][cb+3] + G[cg2][3][b][cb+3] + gb1[3];
            c1r = fsig(g1) * c1r + fsig(g0) * tanhf(g2);
            float h = fsig(g3) * tanhf(c1r);
            hstage[b][jl] = __float2bfloat16(h);
        }
        __syncthreads();
        if (tid < 32)
            cstore16((void*)(H1t + (size_t)tid * HH + bid * 8), *(const u32x4*)&hstage[tid][0]);
        grid_barrier(bar, bid, gen);

        // ======== S2: gates2 += Wih2*h1(t); pre-acc gates1(t+1) += Whh1*h1(t) ========
        #pragma unroll
        for (int s = 0; s < 8; ++s) {
            int k0 = kq * 256 + s * 32 + l4 * 8;
            fA[s] = *(const bf16x8*)(H1t + (size_t)l15 * HH + k0);
            fB[s] = *(const bf16x8*)(H1t + (size_t)(16 + l15) * HH + k0);
        }
        #pragma unroll
        for (int s = 0; s < 8; ++s) {
            acc2A = MFMA(fA[s], w2a[s], acc2A);
            acc2B = MFMA(fB[s], w2a[s], acc2B);
            acc1A = MFMA(fA[s], w1h[s], acc1A);
            acc1B = MFMA(fB[s], w1h[s], acc1B);
        }
        #pragma unroll
        for (int r = 0; r < 4; ++r) {
            G[cg][kq][l4 * 4 + r][l15]      = acc2A[r];
            G[cg][kq][16 + l4 * 4 + r][l15] = acc2B[r];
        }
        acc2A = (f32x4){0,0,0,0}; acc2B = (f32x4){0,0,0,0};
        __syncthreads();
        if (tid < 256) {
            int b = tid >> 3, jl = tid & 7;
            int cg2 = jl >> 2, cb = (jl & 3) * 4;
            float g0 = G[cg2][0][b][cb+0] + G[cg2][1][b][cb+0] + G[cg2][2][b][cb+0] + G[cg2][3][b][cb+0] + gb2[0];
            float g1 = G[cg2][0][b][cb+1] + G[cg2][1][b][cb+1] + G[cg2][2][b][cb+1] + G[cg2][3][b][cb+1] + gb2[1];
            float g2 = G[cg2][0][b][cb+2] + G[cg2][1][b][cb+2] + G[cg2][2][b][cb+2] + G[cg2][3][b][cb+2] + gb2[2];
            float g3 = G[cg2][0][b][cb+3] + G[cg2][1][b][cb+3] + G[cg2][2][b][cb+3] + G[cg2][3][b][cb+3] + gb2[3];
            c2r = fsig(g1) * c2r + fsig(g0) * tanhf(g2);
            float h = fsig(g3) * tanhf(c2r);
            hstage[b][jl]  = __float2bfloat16(h);
            hstagef[b][jl] = h;
        }
        __syncthreads();
        if (tid < 32) {
            u32x4 v = *(const u32x4*)&hstage[tid][0];
            cstore16((void*)(H2t + (size_t)tid * HH + bid * 8), v);
            *(u32x4*)(AlogT + (size_t)tid * KLOG + bid * 8) = v;   // normal store
            cstore16(h2f + (size_t)tid * HH + bid * 8,     *(const u32x4*)&hstagef[tid][0]);
            cstore16(h2f + (size_t)tid * HH + bid * 8 + 4, *(const u32x4*)&hstagef[tid][4]);
        }
        grid_barrier(bar, bid, gen);

        // ======== S3: pre-acc gates2(t+1) += Whh2*h2(t) (+ emb(t+1));  attn ========
        #pragma unroll
        for (int s = 0; s < 8; ++s) {
            int k0 = kq * 256 + s * 32 + l4 * 8;
            fA[s] = *(const bf16x8*)(H2t + (size_t)l15 * HH + k0);
            fB[s] = *(const bf16x8*)(H2t + (size_t)(16 + l15) * HH + k0);
        }
        #pragma unroll
        for (int s = 0; s < 8; ++s) {
            acc2A = MFMA(fA[s], w2b[s], acc2A);
            acc2B = MFMA(fB[s], w2b[s], acc2B);
        }
        if (t + 1 < TT) {                                   // emb(t+1) pre-acc
            const __hip_bfloat16* An = Aemb + (size_t)(t + 1) * BB * EE;
            #pragma unroll
            for (int s = 0; s < 4; ++s) {
                int k0 = kq * 128 + s * 32 + l4 * 8;
                bf16x8 a0 = *(const bf16x8*)(An + (size_t)l15 * EE + k0);
                bf16x8 a1 = *(const bf16x8*)(An + (size_t)(16 + l15) * EE + k0);
                acc1A = MFMA(a0, w1e[s], acc1A);
                acc1B = MFMA(a1, w1e[s], acc1B);
            }
        }

        if (bid < NATT) {
            const int b = bid;
            if (tid < 256) {            // stage h2(t) fp32 -> LDS (coherent read)
                f32x4 hv;
                cload_f4(hv, h2f + (size_t)b * HH + tid * 4);
                VMCNT0;
                *(f32x4*)&hs[tid * 4] = hv;
            }
            __syncthreads();
            {   // q[k'] = Wq[k',:] . h2 + bq   (4 threads per k', fp32)
                int kp = tid >> 2, qc = tid & 3;
                const float4* wr = (const float4*)(Wq + (size_t)kp * HH + qc * 256);
                const float* hh = hs + qc * 256;
                float acc = 0.f;
                #pragma unroll 4
                for (int c = 0; c < 64; ++c) {
                    float4 wv4 = wr[c];
                    acc += wv4.x*hh[c*4] + wv4.y*hh[c*4+1] + wv4.z*hh[c*4+2] + wv4.w*hh[c*4+3];
                }
                red[tid] = acc;
            }
            __syncthreads();
            if (tid < KK) qs[tid] = red[tid*4] + red[tid*4+1] + red[tid*4+2] + red[tid*4+3] + bq[tid];
            __syncthreads();
            {   // energy[s] = keys[b,s,:] . q   (2 threads per s)
                int s = tid >> 1, hf = tid & 1;
                const float4* kr = (const float4*)(keys + ((size_t)b * SS + s) * KK + hf * 64);
                const float* qh = qs + hf * 64;
                float acc = 0.f;
                #pragma unroll
                for (int k4 = 0; k4 < 16; ++k4) {
                    float4 kv = kr[k4];
                    acc += kv.x*qh[k4*4] + kv.y*qh[k4*4+1] + kv.z*qh[k4*4+2] + kv.w*qh[k4*4+3];
                }
                red[tid] = acc;
            }
            __syncthreads();
            if (tid < SS) es[tid] = red[tid*2] + red[tid*2+1];
            __syncthreads();
            if (tid < SS) red[tid] = es[tid];
            __syncthreads();
            for (int off = 128; off > 0; off >>= 1) {
                if (tid < off) red[tid] = fmaxf(red[tid], red[tid + off]);
                __syncthreads();
            }
            float mx = red[0];
            __syncthreads();
            if (tid < SS) { float ev = __expf(es[tid] - mx); es[tid] = ev; red[tid] = ev; }
            __syncthreads();
            for (int off = 128; off > 0; off >>= 1) {
                if (tid < off) red[tid] += red[tid + off];
                __syncthreads();
            }
            float inv = 1.f / red[0];
            __syncthreads();
            {   // ctx[v] = sum_s es[s]*vals[b,s,v]  (4 threads per v, s-quarters)
                int v = tid & 127, sh = tid >> 7;
                const float* vb = vals + ((size_t)b * SS + sh * 64) * VV + v;
                float acc = 0.f;
                for (int i = 0; i < 64; ++i) acc += es[sh * 64 + i] * vb[(size_t)i * VV];
                red[tid] = acc;
            }
            __syncthreads();
            if (tid < VV) {
                float cv = (red[tid] + red[tid+128] + red[tid+256] + red[tid+384]) * inv;
                cstage[tid] = __float2bfloat16(cv);
            }
            __syncthreads();
            if (tid < 16) {
                u32x4 v = *(const u32x4*)&cstage[tid * 8];
                cstore16((void*)(CTXs + (size_t)(t + 1) * BB * VV + (size_t)b * VV + tid * 8), v);
                *(u32x4*)(AlogT + (size_t)b * KLOG + HH + tid * 8) = v;  // normal store
            }
        }
        grid_barrier(bar, bid, gen);
    }
}

// ---------------- deferred logits GEMM ----------------
__global__ __launch_bounds__(256) void logits_gemm(
    const __hip_bfloat16* __restrict__ Alog,
    const __hip_bfloat16* __restrict__ W,
    const float* __restrict__ bout,
    float* __restrict__ out)
{
    int n0 = blockIdx.x * 128;
    int m0 = blockIdx.y * 128;
    int wv = threadIdx.x >> 6, l = threadIdx.x & 63;
    int l15 = l & 15, l4 = l >> 4;

    f32x4 acc[8][2] = {};
    const __hip_bfloat16* Ap = Alog + (size_t)(m0 + l15) * KLOG + l4 * 8;
    const __hip_bfloat16* Bp = W    + (size_t)(n0 + wv * 32 + l15) * KLOG + l4 * 8;

    for (int kt = 0; kt < KLOG; kt += 32) {
        bf16x8 b0 = *(const bf16x8*)(Bp + kt);
        bf16x8 b1 = *(const bf16x8*)(Bp + (size_t)16 * KLOG + kt);
        #pragma unroll
        for (int ms = 0; ms < 8; ++ms) {
            bf16x8 a = *(const bf16x8*)(Ap + (size_t)ms * 16 * KLOG + kt);
            acc[ms][0] = MFMA(a, b0, acc[ms][0]);
            acc[ms][1] = MFMA(a, b1, acc[ms][1]);
        }
    }
    #pragma unroll
    for (int ms = 0; ms < 8; ++ms)
        #pragma unroll
        for (int ns = 0; ns < 2; ++ns) {
            int col = n0 + wv * 32 + ns * 16 + l15;
            if (col < VOC) {
                float bias = bout[col];
                #pragma unroll
                for (int r = 0; r < 4; ++r) {
                    int m = m0 + ms * 16 + l4 * 4 + r;
                    int b = m & 31, t = m >> 5;
                    out[((size_t)b * TT + t) * VOC + col] = acc[ms][ns][r] + bias;
                }
            }
        }
}

// ---------------- host ----------------
extern "C" void kernel_launch(void* const* d_in, const int* in_sizes, int n_in,
                              void* d_out, int out_size, void* d_ws, size_t ws_size,
                              hipStream_t stream)
{
    (void)in_sizes; (void)n_in; (void)out_size; (void)ws_size;
    const int*   dec  = (const int*)  d_in[0];
    const float* enc  = (const float*)d_in[2];
    const float* keys = (const float*)d_in[3];
    const float* vals = (const float*)d_in[4];
    const float* emb  = (const float*)d_in[5];
    const float* Wih1 = (const float*)d_in[6];
    const float* Whh1 = (const float*)d_in[7];
    const float* b1   = (const float*)d_in[8];
    const float* Wih2 = (const float*)d_in[9];
    const float* Whh2 = (const float*)d_in[10];
    const float* b2   = (const float*)d_in[11];
    const float* Wq   = (const float*)d_in[12];
    const float* bq   = (const float*)d_in[13];
    const float* Wout = (const float*)d_in[14];
    const float* bout = (const float*)d_in[15];
    float* out = (float*)d_out;

    // workspace carve (~50 MB)
    char* p = (char*)d_ws;
    __hip_bfloat16* WoutP = (__hip_bfloat16*)p; p += (size_t)VOCP * KLOG * 2;          // 18.6 MB
    __hip_bfloat16* Alog  = (__hip_bfloat16*)p; p += (size_t)TT * BB * KLOG * 2;       // 9.4 MB
    __hip_bfloat16* Aemb  = (__hip_bfloat16*)p; p += (size_t)TT * BB * EE * 2;         // 4.2 MB
    __hip_bfloat16* H1s   = (__hip_bfloat16*)p; p += (size_t)(TT + 1) * BB * HH * 2;   // 8.45 MB
    __hip_bfloat16* H2s   = (__hip_bfloat16*)p; p += (size_t)(TT + 1) * BB * HH * 2;   // 8.45 MB
    __hip_bfloat16* CTXs  = (__hip_bfloat16*)p; p += (size_t)(TT + 1) * BB * VV * 2;   // 1.06 MB
    float* h2f = (float*)p; p += (size_t)BB * HH * 4;                                  // 128 KB
    int* bar = (int*)p; p += 4096;

    pack_wout  <<<dim3((KLOG + 255) / 256, VOCP), 256, 0, stream>>>(Wout, WoutP);
    init_state <<<dim3(128), 256, 0, stream>>>(enc, H1s, H2s, bar);
    gather_emb <<<dim3(TT * BB), 256, 0, stream>>>(dec, emb, Aemb);

    decoder_persistent<<<dim3(NB2), 512, 0, stream>>>(
        Wih1, Whh1, b1, Wih2, Whh2, b2, Wq, bq, keys, vals,
        Aemb, H1s, H2s, CTXs, h2f, Alog, bar);

    logits_gemm<<<dim3(VOCP / 128, (BB * TT) / 128), 256, 0, stream>>>(Alog, WoutP, bout, out);
}

// Round 9
// 5375.555 us; speedup vs baseline: 1.6864x; 1.4573x over previous
//
#include <hip/hip_runtime.h>
#include <hip/hip_bf16.h>
#include <cstddef>

// ---------------- problem constants ----------------
#define BB    32
#define T1    129
#define TT    128
#define SS    256
#define EE    512
#define HH    1024
#define KK    128
#define VV    128
#define VOC   8000
#define VOCP  8064
#define KLOG  1152          // H + V
#define NB2   128           // persistent grid
#define NATT  32

typedef __bf16 bf16x8 __attribute__((ext_vector_type(8)));
typedef float  f32x4  __attribute__((ext_vector_type(4)));
typedef unsigned int u32x4 __attribute__((ext_vector_type(4)));

#define MFMA(a,b,c) __builtin_amdgcn_mfma_f32_16x16x32_bf16((a),(b),(c),0,0,0)
#define VMCNT0 do { asm volatile("s_waitcnt vmcnt(0)" ::: "memory"); \
                    __builtin_amdgcn_sched_barrier(0); } while (0)

// Coherent (cross-XCD) primitives. Writes go through to the memory-side
// cache (MALL); the matching reads are NORMAL cached loads of addresses that
// are single-use within the dispatch (step-indexed buffers), so the reader's
// L2 cannot hold a stale copy. Only h2f and the barrier word use coherent
// reads (tiny traffic).
__device__ __forceinline__ void cload_f4(f32x4& d, const float* p) {
    asm volatile("global_load_dwordx4 %0, %1, off sc0 sc1" : "=v"(d) : "v"(p));
}
__device__ __forceinline__ int coh_load_i32(const int* p) {
    int r;
    asm volatile("global_load_dword %0, %1, off sc0 sc1\n\ts_waitcnt vmcnt(0)"
                 : "=v"(r) : "v"(p) : "memory");
    return r;
}
__device__ __forceinline__ void cstore16(const void* p, u32x4 v) {
    asm volatile("global_store_dwordx4 %0, %1, off sc0 sc1" :: "v"(p), "v"(v) : "memory");
}

union bf8u { __hip_bfloat16 h[8]; bf16x8 v; };

__device__ __forceinline__ bf16x8 cvt8(float4 a, float4 b) {
    bf8u u;
    u.h[0] = __float2bfloat16(a.x); u.h[1] = __float2bfloat16(a.y);
    u.h[2] = __float2bfloat16(a.z); u.h[3] = __float2bfloat16(a.w);
    u.h[4] = __float2bfloat16(b.x); u.h[5] = __float2bfloat16(b.y);
    u.h[6] = __float2bfloat16(b.z); u.h[7] = __float2bfloat16(b.w);
    return u.v;
}
__device__ __forceinline__ float fsig(float x) { return 1.f / (1.f + __expf(-x)); }

// ---------------- single-counter monotonic grid barrier ----------------
// Each block adds 1 per round; pollers wait for count >= NB2*round.
// A block cannot arrive at round r+1 before round r's quorum is complete,
// so the target cannot be reached early. One dependent MALL RTT tail.
__device__ __forceinline__ void grid_barrier(int* bar, int& round)
{
    asm volatile("s_waitcnt vmcnt(0)" ::: "memory");   // drain my coherent stores
    __syncthreads();
    if (threadIdx.x == 0) {
        ++round;
        int target = NB2 * round;
        int prev = __hip_atomic_fetch_add(bar, 1, __ATOMIC_RELAXED,
                                          __HIP_MEMORY_SCOPE_AGENT);
        if (prev + 1 < target) {
            while (coh_load_i32(bar) < target)
                __builtin_amdgcn_s_sleep(2);
        }
    }
    __syncthreads();
    asm volatile("" ::: "memory");     // keep post-barrier loads below the barrier
}

// ---------------- prologue kernels ----------------
__global__ void pack_wout(const float* __restrict__ W, __hip_bfloat16* __restrict__ Wp)
{
    int v = blockIdx.y;
    int k = blockIdx.x * 256 + threadIdx.x;
    if (k >= KLOG) return;
    float w = (v < VOC) ? W[(size_t)v * KLOG + k] : 0.f;
    Wp[(size_t)v * KLOG + k] = __float2bfloat16(w);
}

__global__ void init_state(const float* __restrict__ enc,
                           __hip_bfloat16* __restrict__ H1s,
                           __hip_bfloat16* __restrict__ H2s,
                           int* __restrict__ bar)
{
    int i = blockIdx.x * 256 + threadIdx.x;
    if (i < 1024) bar[i] = 0;
    if (i >= BB * HH) return;
    __hip_bfloat16 eb = __float2bfloat16(enc[i]);
    H1s[i] = eb;   // slot 0 = h1(-1)
    H2s[i] = eb;   // slot 0 = h2(-1)
}

__global__ void gather_emb(const int* __restrict__ tok, const float* __restrict__ emb,
                           __hip_bfloat16* __restrict__ Aemb)
{
    int bid = blockIdx.x;          // t*32 + b
    int t = bid >> 5, b = bid & 31;
    int id = tok[b * T1 + t];
    const float* er = emb + (size_t)id * EE;
    __hip_bfloat16* dst = Aemb + (size_t)bid * EE;
    for (int k = threadIdx.x; k < EE; k += 256)
        dst[k] = __float2bfloat16(er[k]);
}

// ---------------- persistent decoder ----------------
// 128 blocks x 512 threads. 8 waves = (cg in 0..1) x (kq in 0..3).
// Block owns 32 packed gate-cols = 8 hidden units.
__global__ __launch_bounds__(512, 2) void decoder_persistent(
    const float* __restrict__ Wih1, const float* __restrict__ Whh1, const float* __restrict__ b1v,
    const float* __restrict__ Wih2, const float* __restrict__ Whh2, const float* __restrict__ b2v,
    const float* __restrict__ Wq,   const float* __restrict__ bq,
    const float* __restrict__ keys, const float* __restrict__ vals,
    const __hip_bfloat16* __restrict__ Aemb,
    __hip_bfloat16* H1s, __hip_bfloat16* H2s, __hip_bfloat16* CTXs,
    float* h2f, __hip_bfloat16* Alog, int* bar)
{
    const int bid = blockIdx.x;
    const int tid = threadIdx.x;
    const int w   = tid >> 6;
    const int cg  = w >> 2;
    const int kq  = w & 3;
    const int l   = tid & 63;
    const int l15 = l & 15, l4 = l >> 4;
    const int n0  = bid * 32 + cg * 16;

    __shared__ float G[2][4][32][17];                 // [cg][kq][batch][col]
    __shared__ alignas(16) __hip_bfloat16 hstage[32][8];
    __shared__ alignas(16) float hstagef[32][8];
    __shared__ alignas(16) __hip_bfloat16 cstage[128];
    __shared__ alignas(16) float hs[HH];
    __shared__ float qs[KK];
    __shared__ float esl[SS];
    __shared__ float red[512];
    __shared__ float wmx[4], wsm[4];

    // ---- weight fragments in registers ----
    bf16x8 w1e[4], w1c, w1h[8], w2a[8], w2b[8];
    {
        const int col  = n0 + l15;
        const int orow = (col & 3) * HH + (col >> 2);   // packed rp=4j+g -> g*H+j
        #pragma unroll
        for (int s = 0; s < 4; ++s) {                   // emb section of W_ih1
            int k0 = kq * 128 + s * 32 + l4 * 8;
            const float* p0 = Wih1 + (size_t)orow * (EE + VV) + k0;
            w1e[s] = cvt8(*(const float4*)p0, *(const float4*)(p0 + 4));
        }
        {                                               // ctx section of W_ih1
            int k0 = kq * 32 + l4 * 8;
            const float* p0 = Wih1 + (size_t)orow * (EE + VV) + EE + k0;
            w1c = cvt8(*(const float4*)p0, *(const float4*)(p0 + 4));
        }
        #pragma unroll
        for (int s = 0; s < 8; ++s) {
            int k0 = kq * 256 + s * 32 + l4 * 8;
            const float* p1 = Whh1 + (size_t)orow * HH + k0;
            const float* p2 = Wih2 + (size_t)orow * HH + k0;
            const float* p3 = Whh2 + (size_t)orow * HH + k0;
            w1h[s] = cvt8(*(const float4*)p1, *(const float4*)(p1 + 4));
            w2a[s] = cvt8(*(const float4*)p2, *(const float4*)(p2 + 4));
            w2b[s] = cvt8(*(const float4*)p3, *(const float4*)(p3 + 4));
        }
    }

    // ---- cell-thread state (tid<256: b = tid>>3, jl = tid&7) ----
    float c1r = 0.f, c2r = 0.f;
    float gb1[4], gb2[4];
    {
        int jl = tid & 7;
        int j  = bid * 8 + jl;
        #pragma unroll
        for (int g = 0; g < 4; ++g) { gb1[g] = b1v[g * HH + j]; gb2[g] = b2v[g * HH + j]; }
    }

    // ---- prologue pre-acc (all normal loads; these slots are never overwritten):
    //      acc1 = Wemb*emb(0) + Whh1*h1(-1);  acc2 = Whh2*h2(-1)
    f32x4 acc1A = {0,0,0,0}, acc1B = {0,0,0,0}, acc2A = {0,0,0,0}, acc2B = {0,0,0,0};
    #pragma unroll
    for (int s = 0; s < 4; ++s) {
        int k0 = kq * 128 + s * 32 + l4 * 8;
        bf16x8 a0 = *(const bf16x8*)(Aemb + (size_t)l15 * EE + k0);
        bf16x8 a1 = *(const bf16x8*)(Aemb + (size_t)(16 + l15) * EE + k0);
        acc1A = MFMA(a0, w1e[s], acc1A);
        acc1B = MFMA(a1, w1e[s], acc1B);
    }
    #pragma unroll
    for (int s = 0; s < 8; ++s) {
        int k0 = kq * 256 + s * 32 + l4 * 8;
        bf16x8 a0 = *(const bf16x8*)(H1s + (size_t)l15 * HH + k0);
        bf16x8 a1 = *(const bf16x8*)(H1s + (size_t)(16 + l15) * HH + k0);
        acc1A = MFMA(a0, w1h[s], acc1A);
        acc1B = MFMA(a1, w1h[s], acc1B);
        bf16x8 b0 = *(const bf16x8*)(H2s + (size_t)l15 * HH + k0);
        bf16x8 b1 = *(const bf16x8*)(H2s + (size_t)(16 + l15) * HH + k0);
        acc2A = MFMA(b0, w2b[s], acc2A);
        acc2B = MFMA(b1, w2b[s], acc2B);
    }

    int round = 0;
    // RACE FIX (kept from round 7): S1 of t=0 overwrites... here slot buffers
    // are step-indexed so slot 0 is never overwritten, but keep the barrier so
    // no block's S1 stores (slot 1, write-through) race ahead of prologue
    // reads of inputs in other blocks' caches. Cheap (1 barrier).
    grid_barrier(bar, round);

    bf16x8 fA[8], fB[8];

    #pragma unroll 1
    for (int t = 0; t < TT; ++t) {
        __hip_bfloat16* AlogT = Alog + (size_t)t * BB * KLOG;
        const __hip_bfloat16* H1t = H1s + (size_t)(t + 1) * BB * HH;   // h1(t) slot
        const __hip_bfloat16* H2t = H2s + (size_t)(t + 1) * BB * HH;   // h2(t) slot

        // ======== S1: + Wctx*ctx(t-1), cell1 -> h1(t) ========
        if (t > 0) {
            const __hip_bfloat16* Ct = CTXs + (size_t)t * BB * VV;     // ctx(t-1)
            int k0 = kq * 32 + l4 * 8;
            bf16x8 a0 = *(const bf16x8*)(Ct + (size_t)l15 * VV + k0);
            bf16x8 a1 = *(const bf16x8*)(Ct + (size_t)(16 + l15) * VV + k0);
            acc1A = MFMA(a0, w1c, acc1A);
            acc1B = MFMA(a1, w1c, acc1B);
        }
        #pragma unroll
        for (int r = 0; r < 4; ++r) {
            G[cg][kq][l4 * 4 + r][l15]      = acc1A[r];
            G[cg][kq][16 + l4 * 4 + r][l15] = acc1B[r];
        }
        acc1A = (f32x4){0,0,0,0}; acc1B = (f32x4){0,0,0,0};
        __syncthreads();
        if (tid < 256) {
            int b = tid >> 3, jl = tid & 7;
            int cg2 = jl >> 2, cb = (jl & 3) * 4;
            float g0 = G[cg2][0][b][cb+0] + G[cg2][1][b][cb+0] + G[cg2][2][b][cb+0] + G[cg2][3][b][cb+0] + gb1[0];
            float g1 = G[cg2][0][b][cb+1] + G[cg2][1][b][cb+1] + G[cg2][2][b][cb+1] + G[cg2][3][b][cb+1] + gb1[1];
            float g2 = G[cg2][0][b][cb+2] + G[cg2][1][b][cb+2] + G[cg2][2][b][cb+2] + G[cg2][3][b][cb+2] + gb1[2];
            float g3 = G[cg2][0][b][cb+3] + G[cg2][1][b][cb+3] + G[cg2][2][b][cb+3] + G[cg2][3][b][cb+3] + gb1[3];
            c1r = fsig(g1) * c1r + fsig(g0) * tanhf(g2);
            float h = fsig(g3) * tanhf(c1r);
            hstage[b][jl] = __float2bfloat16(h);
        }
        __syncthreads();
        if (tid < 32)
            cstore16((void*)(H1t + (size_t)tid * HH + bid * 8), *(const u32x4*)&hstage[tid][0]);
        grid_barrier(bar, round);

        // ======== S2: gates2 += Wih2*h1(t); pre-acc gates1(t+1) += Whh1*h1(t) ========
        #pragma unroll
        for (int s = 0; s < 8; ++s) {
            int k0 = kq * 256 + s * 32 + l4 * 8;
            fA[s] = *(const bf16x8*)(H1t + (size_t)l15 * HH + k0);
            fB[s] = *(const bf16x8*)(H1t + (size_t)(16 + l15) * HH + k0);
        }
        #pragma unroll
        for (int s = 0; s < 8; ++s) {
            acc2A = MFMA(fA[s], w2a[s], acc2A);
            acc2B = MFMA(fB[s], w2a[s], acc2B);
            acc1A = MFMA(fA[s], w1h[s], acc1A);
            acc1B = MFMA(fB[s], w1h[s], acc1B);
        }
        #pragma unroll
        for (int r = 0; r < 4; ++r) {
            G[cg][kq][l4 * 4 + r][l15]      = acc2A[r];
            G[cg][kq][16 + l4 * 4 + r][l15] = acc2B[r];
        }
        acc2A = (f32x4){0,0,0,0}; acc2B = (f32x4){0,0,0,0};
        __syncthreads();
        if (tid < 256) {
            int b = tid >> 3, jl = tid & 7;
            int cg2 = jl >> 2, cb = (jl & 3) * 4;
            float g0 = G[cg2][0][b][cb+0] + G[cg2][1][b][cb+0] + G[cg2][2][b][cb+0] + G[cg2][3][b][cb+0] + gb2[0];
            float g1 = G[cg2][0][b][cb+1] + G[cg2][1][b][cb+1] + G[cg2][2][b][cb+1] + G[cg2][3][b][cb+1] + gb2[1];
            float g2 = G[cg2][0][b][cb+2] + G[cg2][1][b][cb+2] + G[cg2][2][b][cb+2] + G[cg2][3][b][cb+2] + gb2[2];
            float g3 = G[cg2][0][b][cb+3] + G[cg2][1][b][cb+3] + G[cg2][2][b][cb+3] + G[cg2][3][b][cb+3] + gb2[3];
            c2r = fsig(g1) * c2r + fsig(g0) * tanhf(g2);
            float h = fsig(g3) * tanhf(c2r);
            hstage[b][jl]  = __float2bfloat16(h);
            hstagef[b][jl] = h;
        }
        __syncthreads();
        if (tid < 32) {
            u32x4 v = *(const u32x4*)&hstage[tid][0];
            cstore16((void*)(H2t + (size_t)tid * HH + bid * 8), v);
            *(u32x4*)(AlogT + (size_t)tid * KLOG + bid * 8) = v;   // normal store
            cstore16(h2f + (size_t)tid * HH + bid * 8,     *(const u32x4*)&hstagef[tid][0]);
            cstore16(h2f + (size_t)tid * HH + bid * 8 + 4, *(const u32x4*)&hstagef[tid][4]);
        }
        grid_barrier(bar, round);

        // ======== S3: pre-acc gates2(t+1) += Whh2*h2(t) (+ emb(t+1));  attn ========
        f32x4 hv;
        const bool doh = (bid < NATT) && (tid < 256);
        if (doh) cload_f4(hv, h2f + (size_t)bid * HH + tid * 4);   // issue early

        #pragma unroll
        for (int s = 0; s < 8; ++s) {
            int k0 = kq * 256 + s * 32 + l4 * 8;
            fA[s] = *(const bf16x8*)(H2t + (size_t)l15 * HH + k0);
            fB[s] = *(const bf16x8*)(H2t + (size_t)(16 + l15) * HH + k0);
        }
        #pragma unroll
        for (int s = 0; s < 8; ++s) {
            acc2A = MFMA(fA[s], w2b[s], acc2A);
            acc2B = MFMA(fB[s], w2b[s], acc2B);
        }
        if (t + 1 < TT) {                                   // emb(t+1) pre-acc
            const __hip_bfloat16* An = Aemb + (size_t)(t + 1) * BB * EE;
            #pragma unroll
            for (int s = 0; s < 4; ++s) {
                int k0 = kq * 128 + s * 32 + l4 * 8;
                bf16x8 a0 = *(const bf16x8*)(An + (size_t)l15 * EE + k0);
                bf16x8 a1 = *(const bf16x8*)(An + (size_t)(16 + l15) * EE + k0);
                acc1A = MFMA(a0, w1e[s], acc1A);
                acc1B = MFMA(a1, w1e[s], acc1B);
            }
        }

        if (bid < NATT) {
            const int b = bid;
            if (tid < 256) {            // h2(t) fp32 -> LDS (load issued above)
                VMCNT0;
                *(f32x4*)&hs[tid * 4] = hv;
            }
            __syncthreads();                                       // (1)
            {   // q partials: 4 threads per k'
                int kp = tid >> 2, qc = tid & 3;
                const float4* wr = (const float4*)(Wq + (size_t)kp * HH + qc * 256);
                const float* hh = hs + qc * 256;
                float acc = 0.f;
                #pragma unroll 4
                for (int c = 0; c < 64; ++c) {
                    float4 wv4 = wr[c];
                    acc += wv4.x*hh[c*4] + wv4.y*hh[c*4+1] + wv4.z*hh[c*4+2] + wv4.w*hh[c*4+3];
                }
                red[tid] = acc;
            }
            __syncthreads();                                       // (2)
            if (tid < KK) qs[tid] = red[tid*4] + red[tid*4+1] + red[tid*4+2] + red[tid*4+3] + bq[tid];
            __syncthreads();                                       // (3)
            float en = 0.f;
            if (tid < SS) {             // full 128-dot per thread
                const float4* kr = (const float4*)(keys + ((size_t)b * SS + tid) * KK);
                float acc = 0.f;
                #pragma unroll
                for (int k4 = 0; k4 < 32; ++k4) {
                    float4 kv = kr[k4];
                    acc += kv.x*qs[k4*4] + kv.y*qs[k4*4+1] + kv.z*qs[k4*4+2] + kv.w*qs[k4*4+3];
                }
                en = acc;
            }
            if (w < 4) {                // wave max over 64 lanes (waves 0-3)
                float m = en;
                #pragma unroll
                for (int off = 32; off > 0; off >>= 1)
                    m = fmaxf(m, __shfl_xor(m, off));
                if (l == 0) wmx[w] = m;
            }
            __syncthreads();                                       // (4)
            float mx = fmaxf(fmaxf(wmx[0], wmx[1]), fmaxf(wmx[2], wmx[3]));
            if (w < 4) {
                float p = __expf(en - mx);
                esl[tid] = p;
                float sm = p;
                #pragma unroll
                for (int off = 32; off > 0; off >>= 1)
                    sm += __shfl_xor(sm, off);
                if (l == 0) wsm[w] = sm;
            }
            __syncthreads();                                       // (5)
            float inv = 1.f / (wsm[0] + wsm[1] + wsm[2] + wsm[3]);
            {   // PV: 4 threads per v over s-quarters
                int v = tid & 127, sh = tid >> 7;
                const float* vb = vals + ((size_t)b * SS + sh * 64) * VV + v;
                float acc = 0.f;
                #pragma unroll 4
                for (int i = 0; i < 64; ++i) acc += esl[sh * 64 + i] * vb[(size_t)i * VV];
                red[tid] = acc;
            }
            __syncthreads();                                       // (6)
            if (tid < VV) {
                float cv = (red[tid] + red[tid+128] + red[tid+256] + red[tid+384]) * inv;
                cstage[tid] = __float2bfloat16(cv);
            }
            __syncthreads();                                       // (7)
            if (tid < 16) {
                u32x4 v = *(const u32x4*)&cstage[tid * 8];
                cstore16((void*)(CTXs + (size_t)(t + 1) * BB * VV + (size_t)b * VV + tid * 8), v);
                *(u32x4*)(AlogT + (size_t)b * KLOG + HH + tid * 8) = v;  // normal store
            }
        }
        grid_barrier(bar, round);
    }
}

// ---------------- deferred logits GEMM ----------------
__global__ __launch_bounds__(256) void logits_gemm(
    const __hip_bfloat16* __restrict__ Alog,
    const __hip_bfloat16* __restrict__ W,
    const float* __restrict__ bout,
    float* __restrict__ out)
{
    int n0 = blockIdx.x * 128;
    int m0 = blockIdx.y * 128;
    int wv = threadIdx.x >> 6, l = threadIdx.x & 63;
    int l15 = l & 15, l4 = l >> 4;

    f32x4 acc[8][2] = {};
    const __hip_bfloat16* Ap = Alog + (size_t)(m0 + l15) * KLOG + l4 * 8;
    const __hip_bfloat16* Bp = W    + (size_t)(n0 + wv * 32 + l15) * KLOG + l4 * 8;

    for (int kt = 0; kt < KLOG; kt += 32) {
        bf16x8 b0 = *(const bf16x8*)(Bp + kt);
        bf16x8 b1 = *(const bf16x8*)(Bp + (size_t)16 * KLOG + kt);
        #pragma unroll
        for (int ms = 0; ms < 8; ++ms) {
            bf16x8 a = *(const bf16x8*)(Ap + (size_t)ms * 16 * KLOG + kt);
            acc[ms][0] = MFMA(a, b0, acc[ms][0]);
            acc[ms][1] = MFMA(a, b1, acc[ms][1]);
        }
    }
    #pragma unroll
    for (int ms = 0; ms < 8; ++ms)
        #pragma unroll
        for (int ns = 0; ns < 2; ++ns) {
            int col = n0 + wv * 32 + ns * 16 + l15;
            if (col < VOC) {
                float bias = bout[col];
                #pragma unroll
                for (int r = 0; r < 4; ++r) {
                    int m = m0 + ms * 16 + l4 * 4 + r;
                    int b = m & 31, t = m >> 5;
                    out[((size_t)b * TT + t) * VOC + col] = acc[ms][ns][r] + bias;
                }
            }
        }
}

// ---------------- host ----------------
extern "C" void kernel_launch(void* const* d_in, const int* in_sizes, int n_in,
                              void* d_out, int out_size, void* d_ws, size_t ws_size,
                              hipStream_t stream)
{
    (void)in_sizes; (void)n_in; (void)out_size; (void)ws_size;
    const int*   dec  = (const int*)  d_in[0];
    const float* enc  = (const float*)d_in[2];
    const float* keys = (const float*)d_in[3];
    const float* vals = (const float*)d_in[4];
    const float* emb  = (const float*)d_in[5];
    const float* Wih1 = (const float*)d_in[6];
    const float* Whh1 = (const float*)d_in[7];
    const float* b1   = (const float*)d_in[8];
    const float* Wih2 = (const float*)d_in[9];
    const float* Whh2 = (const float*)d_in[10];
    const float* b2   = (const float*)d_in[11];
    const float* Wq   = (const float*)d_in[12];
    const float* bq   = (const float*)d_in[13];
    const float* Wout = (const float*)d_in[14];
    const float* bout = (const float*)d_in[15];
    float* out = (float*)d_out;

    // workspace carve (~50 MB)
    char* p = (char*)d_ws;
    __hip_bfloat16* WoutP = (__hip_bfloat16*)p; p += (size_t)VOCP * KLOG * 2;          // 18.6 MB
    __hip_bfloat16* Alog  = (__hip_bfloat16*)p; p += (size_t)TT * BB * KLOG * 2;       // 9.4 MB
    __hip_bfloat16* Aemb  = (__hip_bfloat16*)p; p += (size_t)TT * BB * EE * 2;         // 4.2 MB
    __hip_bfloat16* H1s   = (__hip_bfloat16*)p; p += (size_t)(TT + 1) * BB * HH * 2;   // 8.45 MB
    __hip_bfloat16* H2s   = (__hip_bfloat16*)p; p += (size_t)(TT + 1) * BB * HH * 2;   // 8.45 MB
    __hip_bfloat16* CTXs  = (__hip_bfloat16*)p; p += (size_t)(TT + 1) * BB * VV * 2;   // 1.06 MB
    float* h2f = (float*)p; p += (size_t)BB * HH * 4;                                  // 128 KB
    int* bar = (int*)p; p += 4096;

    pack_wout  <<<dim3((KLOG + 255) / 256, VOCP), 256, 0, stream>>>(Wout, WoutP);
    init_state <<<dim3(128), 256, 0, stream>>>(enc, H1s, H2s, bar);
    gather_emb <<<dim3(TT * BB), 256, 0, stream>>>(dec, emb, Aemb);

    decoder_persistent<<<dim3(NB2), 512, 0, stream>>>(
        Wih1, Whh1, b1, Wih2, Whh2, b2, Wq, bq, keys, vals,
        Aemb, H1s, H2s, CTXs, h2f, Alog, bar);

    logits_gemm<<<dim3(VOCP / 128, (BB * TT) / 128), 256, 0, stream>>>(Alog, WoutP, bout, out);
}

// Round 10
// 5213.490 us; speedup vs baseline: 1.7388x; 1.0311x over previous
//
#include <hip/hip_runtime.h>
#include <hip/hip_bf16.h>
#include <cstddef>

// ---------------- problem constants ----------------
#define BB    32
#define T1    129
#define TT    128
#define SS    256
#define EE    512
#define HH    1024
#define KK    128
#define VV    128
#define VOC   8000
#define VOCP  8064
#define KLOG  1152          // H + V
#define NB2   128           // persistent grid
#define NATT  32

typedef __bf16 bf16x8 __attribute__((ext_vector_type(8)));
typedef float  f32x4  __attribute__((ext_vector_type(4)));
typedef unsigned int u32x4 __attribute__((ext_vector_type(4)));

#define MFMA(a,b,c) __builtin_amdgcn_mfma_f32_16x16x32_bf16((a),(b),(c),0,0,0)
#define VMCNT0 do { asm volatile("s_waitcnt vmcnt(0)" ::: "memory"); \
                    __builtin_amdgcn_sched_barrier(0); } while (0)

// Coherent (cross-XCD) primitives. Writes go through to the memory-side
// cache (MALL); the matching reads are NORMAL cached loads of addresses that
// are single-use within the dispatch (step-indexed buffers), so the reader's
// L2 cannot hold a stale copy. Only h2f and the barrier word use coherent
// reads (tiny traffic).
__device__ __forceinline__ void cload_f4(f32x4& d, const float* p) {
    asm volatile("global_load_dwordx4 %0, %1, off sc0 sc1" : "=v"(d) : "v"(p));
}
__device__ __forceinline__ int coh_load_i32(const int* p) {
    int r;
    asm volatile("global_load_dword %0, %1, off sc0 sc1\n\ts_waitcnt vmcnt(0)"
                 : "=v"(r) : "v"(p) : "memory");
    return r;
}
__device__ __forceinline__ void cstore16(const void* p, u32x4 v) {
    asm volatile("global_store_dwordx4 %0, %1, off sc0 sc1" :: "v"(p), "v"(v) : "memory");
}

union bf8u { __hip_bfloat16 h[8]; bf16x8 v; };

__device__ __forceinline__ bf16x8 cvt8(float4 a, float4 b) {
    bf8u u;
    u.h[0] = __float2bfloat16(a.x); u.h[1] = __float2bfloat16(a.y);
    u.h[2] = __float2bfloat16(a.z); u.h[3] = __float2bfloat16(a.w);
    u.h[4] = __float2bfloat16(b.x); u.h[5] = __float2bfloat16(b.y);
    u.h[6] = __float2bfloat16(b.z); u.h[7] = __float2bfloat16(b.w);
    return u.v;
}
__device__ __forceinline__ float fsig(float x) { return 1.f / (1.f + __expf(-x)); }

// ---------------- monotonic two-level grid barrier ----------------
// 16 leaf counters (8 blocks each, 128 B apart -> parallel MALL lines,
// max 8 same-address RMWs) + one root counter (16 RMWs total, one per
// completed leaf). Pollers wait root >= 16*round. Monotonic: a leaf cannot
// reach 8*r before all its round-r members arrived; the root cannot reach
// 16*r before all leaves completed round r. No reset, no generation word.
__device__ __forceinline__ void grid_barrier(int* bar, int bid, int& round)
{
    asm volatile("s_waitcnt vmcnt(0)" ::: "memory");   // drain my coherent stores
    __syncthreads();
    if (threadIdx.x == 0) {
        ++round;
        int prev = __hip_atomic_fetch_add(&bar[(bid >> 3) * 32], 1,
                                          __ATOMIC_RELAXED, __HIP_MEMORY_SCOPE_AGENT);
        if (((prev + 1) & 7) == 0)                     // my leaf's quorum done
            __hip_atomic_fetch_add(&bar[512], 1,
                                   __ATOMIC_RELAXED, __HIP_MEMORY_SCOPE_AGENT);
        int target = 16 * round;
        while (coh_load_i32(&bar[512]) < target)
            __builtin_amdgcn_s_sleep(1);
        round = round;
    }
    __syncthreads();
    asm volatile("" ::: "memory");     // keep post-barrier loads below the barrier
}

// ---------------- prologue kernels ----------------
__global__ void pack_wout(const float* __restrict__ W, __hip_bfloat16* __restrict__ Wp)
{
    int v = blockIdx.y;
    int k = blockIdx.x * 256 + threadIdx.x;
    if (k >= KLOG) return;
    float w = (v < VOC) ? W[(size_t)v * KLOG + k] : 0.f;
    Wp[(size_t)v * KLOG + k] = __float2bfloat16(w);
}

__global__ void init_state(const float* __restrict__ enc,
                           __hip_bfloat16* __restrict__ H1s,
                           __hip_bfloat16* __restrict__ H2s,
                           int* __restrict__ bar)
{
    int i = blockIdx.x * 256 + threadIdx.x;
    if (i < 1024) bar[i] = 0;
    if (i >= BB * HH) return;
    __hip_bfloat16 eb = __float2bfloat16(enc[i]);
    H1s[i] = eb;   // slot 0 = h1(-1)
    H2s[i] = eb;   // slot 0 = h2(-1)
}

__global__ void gather_emb(const int* __restrict__ tok, const float* __restrict__ emb,
                           __hip_bfloat16* __restrict__ Aemb)
{
    int bid = blockIdx.x;          // t*32 + b
    int t = bid >> 5, b = bid & 31;
    int id = tok[b * T1 + t];
    const float* er = emb + (size_t)id * EE;
    __hip_bfloat16* dst = Aemb + (size_t)bid * EE;
    for (int k = threadIdx.x; k < EE; k += 256)
        dst[k] = __float2bfloat16(er[k]);
}

// ---------------- persistent decoder ----------------
// 128 blocks x 512 threads. 8 waves = (cg in 0..1) x (kq in 0..3).
// Block owns 32 packed gate-cols = 8 hidden units.
__global__ __launch_bounds__(512, 2) void decoder_persistent(
    const float* __restrict__ Wih1, const float* __restrict__ Whh1, const float* __restrict__ b1v,
    const float* __restrict__ Wih2, const float* __restrict__ Whh2, const float* __restrict__ b2v,
    const float* __restrict__ Wq,   const float* __restrict__ bq,
    const float* __restrict__ keys, const float* __restrict__ vals,
    const __hip_bfloat16* __restrict__ Aemb,
    __hip_bfloat16* H1s, __hip_bfloat16* H2s, __hip_bfloat16* CTXs,
    float* h2f, __hip_bfloat16* Alog, int* bar)
{
    const int bid = blockIdx.x;
    const int tid = threadIdx.x;
    const int w   = tid >> 6;
    const int cg  = w >> 2;
    const int kq  = w & 3;
    const int l   = tid & 63;
    const int l15 = l & 15, l4 = l >> 4;
    const int n0  = bid * 32 + cg * 16;

    __shared__ float G[2][4][32][17];                 // [cg][kq][batch][col]
    __shared__ alignas(16) __hip_bfloat16 hstage[32][8];
    __shared__ alignas(16) float hstagef[32][8];
    __shared__ alignas(16) __hip_bfloat16 cstage[128];
    __shared__ alignas(16) float hs[HH];
    __shared__ float qs[KK];
    __shared__ float esl[SS];
    __shared__ float red[512];
    __shared__ float wmx[4], wsm[4];

    // ---- weight fragments in registers ----
    bf16x8 w1e[4], w1c, w1h[8], w2a[8], w2b[8];
    {
        const int col  = n0 + l15;
        const int orow = (col & 3) * HH + (col >> 2);   // packed rp=4j+g -> g*H+j
        #pragma unroll
        for (int s = 0; s < 4; ++s) {                   // emb section of W_ih1
            int k0 = kq * 128 + s * 32 + l4 * 8;
            const float* p0 = Wih1 + (size_t)orow * (EE + VV) + k0;
            w1e[s] = cvt8(*(const float4*)p0, *(const float4*)(p0 + 4));
        }
        {                                               // ctx section of W_ih1
            int k0 = kq * 32 + l4 * 8;
            const float* p0 = Wih1 + (size_t)orow * (EE + VV) + EE + k0;
            w1c = cvt8(*(const float4*)p0, *(const float4*)(p0 + 4));
        }
        #pragma unroll
        for (int s = 0; s < 8; ++s) {
            int k0 = kq * 256 + s * 32 + l4 * 8;
            const float* p1 = Whh1 + (size_t)orow * HH + k0;
            const float* p2 = Wih2 + (size_t)orow * HH + k0;
            const float* p3 = Whh2 + (size_t)orow * HH + k0;
            w1h[s] = cvt8(*(const float4*)p1, *(const float4*)(p1 + 4));
            w2a[s] = cvt8(*(const float4*)p2, *(const float4*)(p2 + 4));
            w2b[s] = cvt8(*(const float4*)p3, *(const float4*)(p3 + 4));
        }
    }

    // ---- cell-thread state (tid<256: b = tid>>3, jl = tid&7) ----
    float c1r = 0.f, c2r = 0.f;
    float gb1[4], gb2[4];
    {
        int jl = tid & 7;
        int j  = bid * 8 + jl;
        #pragma unroll
        for (int g = 0; g < 4; ++g) { gb1[g] = b1v[g * HH + j]; gb2[g] = b2v[g * HH + j]; }
    }

    // ---- prologue pre-acc (all normal loads; these slots are never overwritten):
    //      acc1 = Wemb*emb(0) + Whh1*h1(-1);  acc2 = Whh2*h2(-1)
    f32x4 acc1A = {0,0,0,0}, acc1B = {0,0,0,0}, acc2A = {0,0,0,0}, acc2B = {0,0,0,0};
    #pragma unroll
    for (int s = 0; s < 4; ++s) {
        int k0 = kq * 128 + s * 32 + l4 * 8;
        bf16x8 a0 = *(const bf16x8*)(Aemb + (size_t)l15 * EE + k0);
        bf16x8 a1 = *(const bf16x8*)(Aemb + (size_t)(16 + l15) * EE + k0);
        acc1A = MFMA(a0, w1e[s], acc1A);
        acc1B = MFMA(a1, w1e[s], acc1B);
    }
    #pragma unroll
    for (int s = 0; s < 8; ++s) {
        int k0 = kq * 256 + s * 32 + l4 * 8;
        bf16x8 a0 = *(const bf16x8*)(H1s + (size_t)l15 * HH + k0);
        bf16x8 a1 = *(const bf16x8*)(H1s + (size_t)(16 + l15) * HH + k0);
        acc1A = MFMA(a0, w1h[s], acc1A);
        acc1B = MFMA(a1, w1h[s], acc1B);
        bf16x8 b0 = *(const bf16x8*)(H2s + (size_t)l15 * HH + k0);
        bf16x8 b1 = *(const bf16x8*)(H2s + (size_t)(16 + l15) * HH + k0);
        acc2A = MFMA(b0, w2b[s], acc2A);
        acc2B = MFMA(b1, w2b[s], acc2B);
    }

    int round = 0;
    // Keep one barrier between prologue reads and the first write-through
    // stores of the loop (cheap; avoids any cross-block read/write overlap).
    grid_barrier(bar, bid, round);

    bf16x8 fA[8], fB[8];

    #pragma unroll 1
    for (int t = 0; t < TT; ++t) {
        __hip_bfloat16* AlogT = Alog + (size_t)t * BB * KLOG;
        const __hip_bfloat16* H1t = H1s + (size_t)(t + 1) * BB * HH;   // h1(t) slot
        const __hip_bfloat16* H2t = H2s + (size_t)(t + 1) * BB * HH;   // h2(t) slot

        // ======== S1: + Wctx*ctx(t-1), cell1 -> h1(t) ========
        if (t > 0) {
            const __hip_bfloat16* Ct = CTXs + (size_t)t * BB * VV;     // ctx(t-1)
            int k0 = kq * 32 + l4 * 8;
            bf16x8 a0 = *(const bf16x8*)(Ct + (size_t)l15 * VV + k0);
            bf16x8 a1 = *(const bf16x8*)(Ct + (size_t)(16 + l15) * VV + k0);
            acc1A = MFMA(a0, w1c, acc1A);
            acc1B = MFMA(a1, w1c, acc1B);
        }
        #pragma unroll
        for (int r = 0; r < 4; ++r) {
            G[cg][kq][l4 * 4 + r][l15]      = acc1A[r];
            G[cg][kq][16 + l4 * 4 + r][l15] = acc1B[r];
        }
        acc1A = (f32x4){0,0,0,0}; acc1B = (f32x4){0,0,0,0};
        __syncthreads();
        if (tid < 256) {
            int b = tid >> 3, jl = tid & 7;
            int cg2 = jl >> 2, cb = (jl & 3) * 4;
            float g0 = G[cg2][0][b][cb+0] + G[cg2][1][b][cb+0] + G[cg2][2][b][cb+0] + G[cg2][3][b][cb+0] + gb1[0];
            float g1 = G[cg2][0][b][cb+1] + G[cg2][1][b][cb+1] + G[cg2][2][b][cb+1] + G[cg2][3][b][cb+1] + gb1[1];
            float g2 = G[cg2][0][b][cb+2] + G[cg2][1][b][cb+2] + G[cg2][2][b][cb+2] + G[cg2][3][b][cb+2] + gb1[2];
            float g3 = G[cg2][0][b][cb+3] + G[cg2][1][b][cb+3] + G[cg2][2][b][cb+3] + G[cg2][3][b][cb+3] + gb1[3];
            c1r = fsig(g1) * c1r + fsig(g0) * tanhf(g2);
            float h = fsig(g3) * tanhf(c1r);
            hstage[b][jl] = __float2bfloat16(h);
        }
        __syncthreads();
        if (tid < 32)
            cstore16((void*)(H1t + (size_t)tid * HH + bid * 8), *(const u32x4*)&hstage[tid][0]);
        grid_barrier(bar, bid, round);

        // ======== S2: gates2 += Wih2*h1(t); pre-acc gates1(t+1) += Whh1*h1(t) ========
        #pragma unroll
        for (int s = 0; s < 8; ++s) {
            int k0 = kq * 256 + s * 32 + l4 * 8;
            fA[s] = *(const bf16x8*)(H1t + (size_t)l15 * HH + k0);
            fB[s] = *(const bf16x8*)(H1t + (size_t)(16 + l15) * HH + k0);
        }
        #pragma unroll
        for (int s = 0; s < 8; ++s) {
            acc2A = MFMA(fA[s], w2a[s], acc2A);
            acc2B = MFMA(fB[s], w2a[s], acc2B);
            acc1A = MFMA(fA[s], w1h[s], acc1A);
            acc1B = MFMA(fB[s], w1h[s], acc1B);
        }
        #pragma unroll
        for (int r = 0; r < 4; ++r) {
            G[cg][kq][l4 * 4 + r][l15]      = acc2A[r];
            G[cg][kq][16 + l4 * 4 + r][l15] = acc2B[r];
        }
        acc2A = (f32x4){0,0,0,0}; acc2B = (f32x4){0,0,0,0};
        __syncthreads();
        if (tid < 256) {
            int b = tid >> 3, jl = tid & 7;
            int cg2 = jl >> 2, cb = (jl & 3) * 4;
            float g0 = G[cg2][0][b][cb+0] + G[cg2][1][b][cb+0] + G[cg2][2][b][cb+0] + G[cg2][3][b][cb+0] + gb2[0];
            float g1 = G[cg2][0][b][cb+1] + G[cg2][1][b][cb+1] + G[cg2][2][b][cb+1] + G[cg2][3][b][cb+1] + gb2[1];
            float g2 = G[cg2][0][b][cb+2] + G[cg2][1][b][cb+2] + G[cg2][2][b][cb+2] + G[cg2][3][b][cb+2] + gb2[2];
            float g3 = G[cg2][0][b][cb+3] + G[cg2][1][b][cb+3] + G[cg2][2][b][cb+3] + G[cg2][3][b][cb+3] + gb2[3];
            c2r = fsig(g1) * c2r + fsig(g0) * tanhf(g2);
            float h = fsig(g3) * tanhf(c2r);
            hstage[b][jl]  = __float2bfloat16(h);
            hstagef[b][jl] = h;
        }
        __syncthreads();
        if (tid < 32) {
            u32x4 v = *(const u32x4*)&hstage[tid][0];
            cstore16((void*)(H2t + (size_t)tid * HH + bid * 8), v);
            *(u32x4*)(AlogT + (size_t)tid * KLOG + bid * 8) = v;   // normal store
            cstore16(h2f + (size_t)tid * HH + bid * 8,     *(const u32x4*)&hstagef[tid][0]);
            cstore16(h2f + (size_t)tid * HH + bid * 8 + 4, *(const u32x4*)&hstagef[tid][4]);
        }
        grid_barrier(bar, bid, round);

        // ======== S3: pre-acc gates2(t+1) += Whh2*h2(t) (+ emb(t+1));  attn ========
        f32x4 hv;
        const bool doh = (bid < NATT) && (tid < 256);
        if (doh) cload_f4(hv, h2f + (size_t)bid * HH + tid * 4);   // issue early

        #pragma unroll
        for (int s = 0; s < 8; ++s) {
            int k0 = kq * 256 + s * 32 + l4 * 8;
            fA[s] = *(const bf16x8*)(H2t + (size_t)l15 * HH + k0);
            fB[s] = *(const bf16x8*)(H2t + (size_t)(16 + l15) * HH + k0);
        }
        #pragma unroll
        for (int s = 0; s < 8; ++s) {
            acc2A = MFMA(fA[s], w2b[s], acc2A);
            acc2B = MFMA(fB[s], w2b[s], acc2B);
        }
        if (t + 1 < TT) {                                   // emb(t+1) pre-acc
            const __hip_bfloat16* An = Aemb + (size_t)(t + 1) * BB * EE;
            #pragma unroll
            for (int s = 0; s < 4; ++s) {
                int k0 = kq * 128 + s * 32 + l4 * 8;
                bf16x8 a0 = *(const bf16x8*)(An + (size_t)l15 * EE + k0);
                bf16x8 a1 = *(const bf16x8*)(An + (size_t)(16 + l15) * EE + k0);
                acc1A = MFMA(a0, w1e[s], acc1A);
                acc1B = MFMA(a1, w1e[s], acc1B);
            }
        }

        if (bid < NATT) {
            const int b = bid;
            if (tid < 256) {            // h2(t) fp32 -> LDS (load issued above)
                VMCNT0;
                *(f32x4*)&hs[tid * 4] = hv;
            }
            __syncthreads();                                       // (1)
            {   // q partials: 4 threads per k'
                int kp = tid >> 2, qc = tid & 3;
                const float4* wr = (const float4*)(Wq + (size_t)kp * HH + qc * 256);
                const float* hh = hs + qc * 256;
                float acc = 0.f;
                #pragma unroll 4
                for (int c = 0; c < 64; ++c) {
                    float4 wv4 = wr[c];
                    acc += wv4.x*hh[c*4] + wv4.y*hh[c*4+1] + wv4.z*hh[c*4+2] + wv4.w*hh[c*4+3];
                }
                red[tid] = acc;
            }
            __syncthreads();                                       // (2)
            if (tid < KK) qs[tid] = red[tid*4] + red[tid*4+1] + red[tid*4+2] + red[tid*4+3] + bq[tid];
            __syncthreads();                                       // (3)
            float en = 0.f;
            if (tid < SS) {             // full 128-dot per thread
                const float4* kr = (const float4*)(keys + ((size_t)b * SS + tid) * KK);
                float acc = 0.f;
                #pragma unroll
                for (int k4 = 0; k4 < 32; ++k4) {
                    float4 kv = kr[k4];
                    acc += kv.x*qs[k4*4] + kv.y*qs[k4*4+1] + kv.z*qs[k4*4+2] + kv.w*qs[k4*4+3];
                }
                en = acc;
            }
            if (w < 4) {                // wave max over 64 lanes (waves 0-3)
                float m = en;
                #pragma unroll
                for (int off = 32; off > 0; off >>= 1)
                    m = fmaxf(m, __shfl_xor(m, off));
                if (l == 0) wmx[w] = m;
            }
            __syncthreads();                                       // (4)
            float mx = fmaxf(fmaxf(wmx[0], wmx[1]), fmaxf(wmx[2], wmx[3]));
            if (w < 4) {
                float p = __expf(en - mx);
                esl[tid] = p;
                float sm = p;
                #pragma unroll
                for (int off = 32; off > 0; off >>= 1)
                    sm += __shfl_xor(sm, off);
                if (l == 0) wsm[w] = sm;
            }
            __syncthreads();                                       // (5)
            float inv = 1.f / (wsm[0] + wsm[1] + wsm[2] + wsm[3]);
            {   // PV: 4 threads per v over s-quarters
                int v = tid & 127, sh = tid >> 7;
                const float* vb = vals + ((size_t)b * SS + sh * 64) * VV + v;
                float acc = 0.f;
                #pragma unroll 4
                for (int i = 0; i < 64; ++i) acc += esl[sh * 64 + i] * vb[(size_t)i * VV];
                red[tid] = acc;
            }
            __syncthreads();                                       // (6)
            if (tid < VV) {
                float cv = (red[tid] + red[tid+128] + red[tid+256] + red[tid+384]) * inv;
                cstage[tid] = __float2bfloat16(cv);
            }
            __syncthreads();                                       // (7)
            if (tid < 16) {
                u32x4 v = *(const u32x4*)&cstage[tid * 8];
                cstore16((void*)(CTXs + (size_t)(t + 1) * BB * VV + (size_t)b * VV + tid * 8), v);
                *(u32x4*)(AlogT + (size_t)b * KLOG + HH + tid * 8) = v;  // normal store
            }
        }
        grid_barrier(bar, bid, round);
    }
}

// ---------------- deferred logits GEMM ----------------
__global__ __launch_bounds__(256) void logits_gemm(
    const __hip_bfloat16* __restrict__ Alog,
    const __hip_bfloat16* __restrict__ W,
    const float* __restrict__ bout,
    float* __restrict__ out)
{
    int n0 = blockIdx.x * 128;
    int m0 = blockIdx.y * 128;
    int wv = threadIdx.x >> 6, l = threadIdx.x & 63;
    int l15 = l & 15, l4 = l >> 4;

    f32x4 acc[8][2] = {};
    const __hip_bfloat16* Ap = Alog + (size_t)(m0 + l15) * KLOG + l4 * 8;
    const __hip_bfloat16* Bp = W    + (size_t)(n0 + wv * 32 + l15) * KLOG + l4 * 8;

    for (int kt = 0; kt < KLOG; kt += 32) {
        bf16x8 b0 = *(const bf16x8*)(Bp + kt);
        bf16x8 b1 = *(const bf16x8*)(Bp + (size_t)16 * KLOG + kt);
        #pragma unroll
        for (int ms = 0; ms < 8; ++ms) {
            bf16x8 a = *(const bf16x8*)(Ap + (size_t)ms * 16 * KLOG + kt);
            acc[ms][0] = MFMA(a, b0, acc[ms][0]);
            acc[ms][1] = MFMA(a, b1, acc[ms][1]);
        }
    }
    #pragma unroll
    for (int ms = 0; ms < 8; ++ms)
        #pragma unroll
        for (int ns = 0; ns < 2; ++ns) {
            int col = n0 + wv * 32 + ns * 16 + l15;
            if (col < VOC) {
                float bias = bout[col];
                #pragma unroll
                for (int r = 0; r < 4; ++r) {
                    int m = m0 + ms * 16 + l4 * 4 + r;
                    int b = m & 31, t = m >> 5;
                    out[((size_t)b * TT + t) * VOC + col] = acc[ms][ns][r] + bias;
                }
            }
        }
}

// ---------------- host ----------------
extern "C" void kernel_launch(void* const* d_in, const int* in_sizes, int n_in,
                              void* d_out, int out_size, void* d_ws, size_t ws_size,
                              hipStream_t stream)
{
    (void)in_sizes; (void)n_in; (void)out_size; (void)ws_size;
    const int*   dec  = (const int*)  d_in[0];
    const float* enc  = (const float*)d_in[2];
    const float* keys = (const float*)d_in[3];
    const float* vals = (const float*)d_in[4];
    const float* emb  = (const float*)d_in[5];
    const float* Wih1 = (const float*)d_in[6];
    const float* Whh1 = (const float*)d_in[7];
    const float* b1   = (const float*)d_in[8];
    const float* Wih2 = (const float*)d_in[9];
    const float* Whh2 = (const float*)d_in[10];
    const float* b2   = (const float*)d_in[11];
    const float* Wq   = (const float*)d_in[12];
    const float* bq   = (const float*)d_in[13];
    const float* Wout = (const float*)d_in[14];
    const float* bout = (const float*)d_in[15];
    float* out = (float*)d_out;

    // workspace carve (~50 MB)
    char* p = (char*)d_ws;
    __hip_bfloat16* WoutP = (__hip_bfloat16*)p; p += (size_t)VOCP * KLOG * 2;          // 18.6 MB
    __hip_bfloat16* Alog  = (__hip_bfloat16*)p; p += (size_t)TT * BB * KLOG * 2;       // 9.4 MB
    __hip_bfloat16* Aemb  = (__hip_bfloat16*)p; p += (size_t)TT * BB * EE * 2;         // 4.2 MB
    __hip_bfloat16* H1s   = (__hip_bfloat16*)p; p += (size_t)(TT + 1) * BB * HH * 2;   // 8.45 MB
    __hip_bfloat16* H2s   = (__hip_bfloat16*)p; p += (size_t)(TT + 1) * BB * HH * 2;   // 8.45 MB
    __hip_bfloat16* CTXs  = (__hip_bfloat16*)p; p += (size_t)(TT + 1) * BB * VV * 2;   // 1.06 MB
    float* h2f = (float*)p; p += (size_t)BB * HH * 4;                                  // 128 KB
    int* bar = (int*)p; p += 4096;

    pack_wout  <<<dim3((KLOG + 255) / 256, VOCP), 256, 0, stream>>>(Wout, WoutP);
    init_state <<<dim3(128), 256, 0, stream>>>(enc, H1s, H2s, bar);
    gather_emb <<<dim3(TT * BB), 256, 0, stream>>>(dec, emb, Aemb);

    decoder_persistent<<<dim3(NB2), 512, 0, stream>>>(
        Wih1, Whh1, b1, Wih2, Whh2, b2, Wq, bq, keys, vals,
        Aemb, H1s, H2s, CTXs, h2f, Alog, bar);

    logits_gemm<<<dim3(VOCP / 128, (BB * TT) / 128), 256, 0, stream>>>(Alog, WoutP, bout, out);
}

// Round 11
// 4625.412 us; speedup vs baseline: 1.9599x; 1.1271x over previous
//
#include <hip/hip_runtime.h>
#include <hip/hip_bf16.h>
#include <cstddef>

// ---------------- problem constants ----------------
#define BB    32
#define T1    129
#define TT    128
#define SS    256
#define EE    512
#define HH    1024
#define KK    128
#define VV    128
#define VOC   8000
#define VOCP  8064
#define KLOG  1152          // H + V
#define NB2   128           // persistent grid
#define NATT  32

typedef __bf16 bf16x8 __attribute__((ext_vector_type(8)));
typedef float  f32x4  __attribute__((ext_vector_type(4)));
typedef unsigned int u32x4 __attribute__((ext_vector_type(4)));
typedef int    i32x2  __attribute__((ext_vector_type(2)));

#define MFMA(a,b,c) __builtin_amdgcn_mfma_f32_16x16x32_bf16((a),(b),(c),0,0,0)
#define VMCNT0 do { asm volatile("s_waitcnt vmcnt(0)" ::: "memory"); \
                    __builtin_amdgcn_sched_barrier(0); } while (0)

// Coherent (cross-XCD) primitives. Producers write through to the memory-side
// cache (MALL); consumers use NORMAL cached loads of step-indexed single-use
// addresses (L2 can't hold a stale copy), so broadcasts are L2-mediated.
__device__ __forceinline__ void cstore16(const void* p, u32x4 v) {
    asm volatile("global_store_dwordx4 %0, %1, off sc0 sc1" :: "v"(p), "v"(v) : "memory");
}
__device__ __forceinline__ void cstore4f(const float* p, float v) {
    asm volatile("global_store_dword %0, %1, off sc0 sc1" :: "v"(p), "v"(v) : "memory");
}
__device__ __forceinline__ void cstore4i(const int* p, int v) {
    asm volatile("global_store_dword %0, %1, off sc0 sc1" :: "v"(p), "v"(v) : "memory");
}

// Flag-array barrier polls (wave 0 only; flags are monotonic step counters).
__device__ __forceinline__ void poll128(const int* flags, int target, int lane)
{
    const int* p = flags + lane * 2;
    for (;;) {
        i32x2 f;
        asm volatile("global_load_dwordx2 %0, %1, off sc0 sc1\n\ts_waitcnt vmcnt(0)"
                     : "=v"(f) : "v"(p) : "memory");
        if (__all(f.x >= target && f.y >= target)) break;
        __builtin_amdgcn_s_sleep(1);
    }
}
__device__ __forceinline__ void poll32(const int* flags, int target, int lane)
{
    const int* p = flags + (lane & 31);
    for (;;) {
        int f;
        asm volatile("global_load_dword %0, %1, off sc0 sc1\n\ts_waitcnt vmcnt(0)"
                     : "=v"(f) : "v"(p) : "memory");
        if (__all(f >= target)) break;
        __builtin_amdgcn_s_sleep(1);
    }
}

union bf8u { __hip_bfloat16 h[8]; bf16x8 v; };

__device__ __forceinline__ bf16x8 cvt8(float4 a, float4 b) {
    bf8u u;
    u.h[0] = __float2bfloat16(a.x); u.h[1] = __float2bfloat16(a.y);
    u.h[2] = __float2bfloat16(a.z); u.h[3] = __float2bfloat16(a.w);
    u.h[4] = __float2bfloat16(b.x); u.h[5] = __float2bfloat16(b.y);
    u.h[6] = __float2bfloat16(b.z); u.h[7] = __float2bfloat16(b.w);
    return u.v;
}
__device__ __forceinline__ float fsig(float x) { return 1.f / (1.f + __expf(-x)); }

// ---------------- prologue kernels ----------------
__global__ void pack_wout(const float* __restrict__ W, __hip_bfloat16* __restrict__ Wp)
{
    int v = blockIdx.y;
    int k = blockIdx.x * 256 + threadIdx.x;
    if (k >= KLOG) return;
    float w = (v < VOC) ? W[(size_t)v * KLOG + k] : 0.f;
    Wp[(size_t)v * KLOG + k] = __float2bfloat16(w);
}

__global__ void init_state(const float* __restrict__ enc,
                           __hip_bfloat16* __restrict__ H1s,
                           __hip_bfloat16* __restrict__ H2s,
                           int* __restrict__ bar)
{
    int i = blockIdx.x * 256 + threadIdx.x;
    if (i < 1024) bar[i] = 0;                 // all flag arrays live in bar[0:1024)
    if (i >= BB * HH) return;
    __hip_bfloat16 eb = __float2bfloat16(enc[i]);
    H1s[i] = eb;   // slot 0 = h1(-1)
    H2s[i] = eb;   // slot 0 = h2(-1)
}

__global__ void gather_emb(const int* __restrict__ tok, const float* __restrict__ emb,
                           __hip_bfloat16* __restrict__ Aemb)
{
    int bid = blockIdx.x;          // t*32 + b
    int t = bid >> 5, b = bid & 31;
    int id = tok[b * T1 + t];
    const float* er = emb + (size_t)id * EE;
    __hip_bfloat16* dst = Aemb + (size_t)bid * EE;
    for (int k = threadIdx.x; k < EE; k += 256)
        dst[k] = __float2bfloat16(er[k]);
}

// ---------------- persistent decoder ----------------
// 128 blocks x 512 threads. 8 waves = (cg in 0..1) x (kq in 0..3).
// Block owns 32 packed gate-cols = 8 hidden units; also owns q-column k'=bid.
__global__ __launch_bounds__(512, 2) void decoder_persistent(
    const float* __restrict__ Wih1, const float* __restrict__ Whh1, const float* __restrict__ b1v,
    const float* __restrict__ Wih2, const float* __restrict__ Whh2, const float* __restrict__ b2v,
    const float* __restrict__ Wq,   const float* __restrict__ bq,
    const float* __restrict__ keys, const float* __restrict__ vals,
    const __hip_bfloat16* __restrict__ Aemb,
    __hip_bfloat16* H1s, __hip_bfloat16* H2s, __hip_bfloat16* CTXs,
    float* h2fs, float* q_s, __hip_bfloat16* Alog, int* bar)
{
    const int bid = blockIdx.x;
    const int tid = threadIdx.x;
    const int w   = tid >> 6;
    const int cg  = w >> 2;
    const int kq  = w & 3;
    const int l   = tid & 63;
    const int l15 = l & 15, l4 = l >> 4;
    const int n0  = bid * 32 + cg * 16;

    int* flag1 = bar;          // 128, h1 ready
    int* flag2 = bar + 128;    // 128, h2 ready
    int* flagq = bar + 256;    // 128, q column ready
    int* flagc = bar + 384;    // 32,  ctx ready

    __shared__ float G[2][4][32][17];
    __shared__ alignas(16) __hip_bfloat16 hstage[32][8];
    __shared__ alignas(16) float hstagef[32][8];
    __shared__ alignas(16) __hip_bfloat16 cstage[128];
    __shared__ float qs[KK];
    __shared__ float esl[SS];
    __shared__ float red[512];
    __shared__ float wmx[4], wsm[4];

    extern __shared__ __hip_bfloat16 kvls[];                 // dynamic 128 KB
    __hip_bfloat16 (*kls)[SS] = (__hip_bfloat16(*)[SS])kvls;           // [KK][SS]
    __hip_bfloat16 (*vls)[VV] = (__hip_bfloat16(*)[VV])(kvls + KK * SS); // [SS][VV]

    // ---- weight fragments in registers ----
    bf16x8 w1e[4], w1c, w1h[8], w2a[8], w2b[8];
    {
        const int col  = n0 + l15;
        const int orow = (col & 3) * HH + (col >> 2);   // packed rp=4j+g -> g*H+j
        #pragma unroll
        for (int s = 0; s < 4; ++s) {
            int k0 = kq * 128 + s * 32 + l4 * 8;
            const float* p0 = Wih1 + (size_t)orow * (EE + VV) + k0;
            w1e[s] = cvt8(*(const float4*)p0, *(const float4*)(p0 + 4));
        }
        {
            int k0 = kq * 32 + l4 * 8;
            const float* p0 = Wih1 + (size_t)orow * (EE + VV) + EE + k0;
            w1c = cvt8(*(const float4*)p0, *(const float4*)(p0 + 4));
        }
        #pragma unroll
        for (int s = 0; s < 8; ++s) {
            int k0 = kq * 256 + s * 32 + l4 * 8;
            const float* p1 = Whh1 + (size_t)orow * HH + k0;
            const float* p2 = Wih2 + (size_t)orow * HH + k0;
            const float* p3 = Whh2 + (size_t)orow * HH + k0;
            w1h[s] = cvt8(*(const float4*)p1, *(const float4*)(p1 + 4));
            w2a[s] = cvt8(*(const float4*)p2, *(const float4*)(p2 + 4));
            w2b[s] = cvt8(*(const float4*)p3, *(const float4*)(p3 + 4));
        }
    }

    // ---- cell-thread state ----
    float c1r = 0.f, c2r = 0.f;
    float gb1[4], gb2[4];
    {
        int jl = tid & 7;
        int j  = bid * 8 + jl;
        #pragma unroll
        for (int g = 0; g < 4; ++g) { gb1[g] = b1v[g * HH + j]; gb2[g] = b2v[g * HH + j]; }
    }

    // ---- attention blocks: keys/vals -> LDS (bf16), once ----
    if (bid < NATT) {
        for (int i = tid; i < SS * KK; i += 512) {
            int s = i >> 7, k = i & 127;
            kls[k][s] = __float2bfloat16(keys[((size_t)bid * SS + s) * KK + k]);
            vls[s][k] = __float2bfloat16(vals[((size_t)bid * SS + s) * VV + k]);
        }
        __syncthreads();
    }

    // ---- prologue pre-acc (slot-0 buffers, never overwritten; normal loads) ----
    f32x4 acc1A = {0,0,0,0}, acc1B = {0,0,0,0}, acc2A = {0,0,0,0}, acc2B = {0,0,0,0};
    #pragma unroll
    for (int s = 0; s < 4; ++s) {
        int k0 = kq * 128 + s * 32 + l4 * 8;
        bf16x8 a0 = *(const bf16x8*)(Aemb + (size_t)l15 * EE + k0);
        bf16x8 a1 = *(const bf16x8*)(Aemb + (size_t)(16 + l15) * EE + k0);
        acc1A = MFMA(a0, w1e[s], acc1A);
        acc1B = MFMA(a1, w1e[s], acc1B);
    }
    #pragma unroll
    for (int s = 0; s < 8; ++s) {
        int k0 = kq * 256 + s * 32 + l4 * 8;
        bf16x8 a0 = *(const bf16x8*)(H1s + (size_t)l15 * HH + k0);
        bf16x8 a1 = *(const bf16x8*)(H1s + (size_t)(16 + l15) * HH + k0);
        acc1A = MFMA(a0, w1h[s], acc1A);
        acc1B = MFMA(a1, w1h[s], acc1B);
        bf16x8 b0 = *(const bf16x8*)(H2s + (size_t)l15 * HH + k0);
        bf16x8 b1 = *(const bf16x8*)(H2s + (size_t)(16 + l15) * HH + k0);
        acc2A = MFMA(b0, w2b[s], acc2A);
        acc2B = MFMA(b1, w2b[s], acc2B);
    }

    bf16x8 fA[8], fB[8];

    #pragma unroll 1
    for (int t = 0; t < TT; ++t) {
        const int rnd = t + 1;
        __hip_bfloat16* AlogT = Alog + (size_t)t * BB * KLOG;
        const __hip_bfloat16* H1t = H1s + (size_t)rnd * BB * HH;
        const __hip_bfloat16* H2t = H2s + (size_t)rnd * BB * HH;
        float* h2ft = h2fs + (size_t)rnd * BB * HH;
        float* qt   = q_s  + (size_t)rnd * BB * KK;

        // ======== S1: + Wctx*ctx(t-1), cell1 -> h1(t) ========
        if (t > 0) {
            const __hip_bfloat16* Ct = CTXs + (size_t)t * BB * VV;
            int k0 = kq * 32 + l4 * 8;
            bf16x8 a0 = *(const bf16x8*)(Ct + (size_t)l15 * VV + k0);
            bf16x8 a1 = *(const bf16x8*)(Ct + (size_t)(16 + l15) * VV + k0);
            acc1A = MFMA(a0, w1c, acc1A);
            acc1B = MFMA(a1, w1c, acc1B);
        }
        #pragma unroll
        for (int r = 0; r < 4; ++r) {
            G[cg][kq][l4 * 4 + r][l15]      = acc1A[r];
            G[cg][kq][16 + l4 * 4 + r][l15] = acc1B[r];
        }
        acc1A = (f32x4){0,0,0,0}; acc1B = (f32x4){0,0,0,0};
        __syncthreads();
        if (tid < 256) {
            int b = tid >> 3, jl = tid & 7;
            int cg2 = jl >> 2, cb = (jl & 3) * 4;
            float g0 = G[cg2][0][b][cb+0] + G[cg2][1][b][cb+0] + G[cg2][2][b][cb+0] + G[cg2][3][b][cb+0] + gb1[0];
            float g1 = G[cg2][0][b][cb+1] + G[cg2][1][b][cb+1] + G[cg2][2][b][cb+1] + G[cg2][3][b][cb+1] + gb1[1];
            float g2 = G[cg2][0][b][cb+2] + G[cg2][1][b][cb+2] + G[cg2][2][b][cb+2] + G[cg2][3][b][cb+2] + gb1[2];
            float g3 = G[cg2][0][b][cb+3] + G[cg2][1][b][cb+3] + G[cg2][2][b][cb+3] + G[cg2][3][b][cb+3] + gb1[3];
            c1r = fsig(g1) * c1r + fsig(g0) * tanhf(g2);
            float h = fsig(g3) * tanhf(c1r);
            hstage[tid >> 3][tid & 7] = __float2bfloat16(h);
        }
        __syncthreads();
        if (tid < 32)
            cstore16((void*)(H1t + (size_t)tid * HH + bid * 8), *(const u32x4*)&hstage[tid][0]);
        VMCNT0;
        if (tid == 0) cstore4i(&flag1[bid], rnd);
        if (w == 0) poll128(flag1, rnd, l);
        __syncthreads();

        // ======== S2: gates2 += Wih2*h1(t); pre-acc gates1(t+1) += Whh1*h1(t) ========
        #pragma unroll
        for (int s = 0; s < 8; ++s) {
            int k0 = kq * 256 + s * 32 + l4 * 8;
            fA[s] = *(const bf16x8*)(H1t + (size_t)l15 * HH + k0);
            fB[s] = *(const bf16x8*)(H1t + (size_t)(16 + l15) * HH + k0);
        }
        #pragma unroll
        for (int s = 0; s < 8; ++s) {
            acc2A = MFMA(fA[s], w2a[s], acc2A);
            acc2B = MFMA(fB[s], w2a[s], acc2B);
            acc1A = MFMA(fA[s], w1h[s], acc1A);
            acc1B = MFMA(fB[s], w1h[s], acc1B);
        }
        #pragma unroll
        for (int r = 0; r < 4; ++r) {
            G[cg][kq][l4 * 4 + r][l15]      = acc2A[r];
            G[cg][kq][16 + l4 * 4 + r][l15] = acc2B[r];
        }
        acc2A = (f32x4){0,0,0,0}; acc2B = (f32x4){0,0,0,0};
        __syncthreads();
        if (tid < 256) {
            int b = tid >> 3, jl = tid & 7;
            int cg2 = jl >> 2, cb = (jl & 3) * 4;
            float g0 = G[cg2][0][b][cb+0] + G[cg2][1][b][cb+0] + G[cg2][2][b][cb+0] + G[cg2][3][b][cb+0] + gb2[0];
            float g1 = G[cg2][0][b][cb+1] + G[cg2][1][b][cb+1] + G[cg2][2][b][cb+1] + G[cg2][3][b][cb+1] + gb2[1];
            float g2 = G[cg2][0][b][cb+2] + G[cg2][1][b][cb+2] + G[cg2][2][b][cb+2] + G[cg2][3][b][cb+2] + gb2[2];
            float g3 = G[cg2][0][b][cb+3] + G[cg2][1][b][cb+3] + G[cg2][2][b][cb+3] + G[cg2][3][b][cb+3] + gb2[3];
            c2r = fsig(g1) * c2r + fsig(g0) * tanhf(g2);
            float h = fsig(g3) * tanhf(c2r);
            hstage[b][jl]  = __float2bfloat16(h);
            hstagef[b][jl] = h;
        }
        __syncthreads();
        if (tid < 32) {
            u32x4 v = *(const u32x4*)&hstage[tid][0];
            cstore16((void*)(H2t + (size_t)tid * HH + bid * 8), v);
            *(u32x4*)(AlogT + (size_t)tid * KLOG + bid * 8) = v;   // normal store
            cstore16(h2ft + (size_t)tid * HH + bid * 8,     *(const u32x4*)&hstagef[tid][0]);
            cstore16(h2ft + (size_t)tid * HH + bid * 8 + 4, *(const u32x4*)&hstagef[tid][4]);
        }
        VMCNT0;
        if (tid == 0) cstore4i(&flag2[bid], rnd);
        if (w == 0) poll128(flag2, rnd, l);
        __syncthreads();

        // ======== S3a: distributed q column (k' = bid) ========
        {
            int b = tid >> 4, c = tid & 15;
            const float4* wr = (const float4*)(Wq + (size_t)bid * HH + c * 64);
            const float4* hr = (const float4*)(h2ft + (size_t)b * HH + c * 64);
            float acc = 0.f;
            #pragma unroll
            for (int i = 0; i < 16; ++i) {
                float4 wv4 = wr[i];
                float4 hv4 = hr[i];
                acc += wv4.x*hv4.x + wv4.y*hv4.y + wv4.z*hv4.z + wv4.w*hv4.w;
            }
            #pragma unroll
            for (int off = 8; off > 0; off >>= 1) acc += __shfl_xor(acc, off);
            if (c == 0) cstore4f(&qt[b * KK + bid], acc);
        }
        VMCNT0;
        __syncthreads();
        if (tid == 0) cstore4i(&flagq[bid], rnd);

        // ======== S3b: pre-acc gates2(t+1) += Whh2*h2(t); + emb(t+1) ========
        #pragma unroll
        for (int s = 0; s < 8; ++s) {
            int k0 = kq * 256 + s * 32 + l4 * 8;
            fA[s] = *(const bf16x8*)(H2t + (size_t)l15 * HH + k0);
            fB[s] = *(const bf16x8*)(H2t + (size_t)(16 + l15) * HH + k0);
        }
        #pragma unroll
        for (int s = 0; s < 8; ++s) {
            acc2A = MFMA(fA[s], w2b[s], acc2A);
            acc2B = MFMA(fB[s], w2b[s], acc2B);
        }
        if (t + 1 < TT) {
            const __hip_bfloat16* An = Aemb + (size_t)(t + 1) * BB * EE;
            #pragma unroll
            for (int s = 0; s < 4; ++s) {
                int k0 = kq * 128 + s * 32 + l4 * 8;
                bf16x8 a0 = *(const bf16x8*)(An + (size_t)l15 * EE + k0);
                bf16x8 a1 = *(const bf16x8*)(An + (size_t)(16 + l15) * EE + k0);
                acc1A = MFMA(a0, w1e[s], acc1A);
                acc1B = MFMA(a1, w1e[s], acc1B);
            }
        }

        // ======== S3c: attention (blocks 0..31) ========
        if (bid < NATT) {
            const int b = bid;
            if (w == 0) poll128(flagq, rnd, l);
            __syncthreads();
            if (tid < KK) qs[tid] = qt[b * KK + tid] + bq[tid];   // normal load (single-use)
            __syncthreads();
            float en = 0.f;
            if (tid < SS) {
                #pragma unroll 8
                for (int k = 0; k < KK; ++k)
                    en += __bfloat162float(kls[k][tid]) * qs[k];
            }
            if (w < 4) {
                float m = en;
                #pragma unroll
                for (int off = 32; off > 0; off >>= 1)
                    m = fmaxf(m, __shfl_xor(m, off));
                if (l == 0) wmx[w] = m;
            }
            __syncthreads();
            float mx = fmaxf(fmaxf(wmx[0], wmx[1]), fmaxf(wmx[2], wmx[3]));
            if (w < 4) {
                float p = __expf(en - mx);
                esl[tid] = p;
                float sm = p;
                #pragma unroll
                for (int off = 32; off > 0; off >>= 1)
                    sm += __shfl_xor(sm, off);
                if (l == 0) wsm[w] = sm;
            }
            __syncthreads();
            float inv = 1.f / (wsm[0] + wsm[1] + wsm[2] + wsm[3]);
            {   // PV from LDS vals (bf16)
                int v = tid & 127, sh = tid >> 7;
                float acc = 0.f;
                #pragma unroll 4
                for (int i = 0; i < 64; ++i)
                    acc += esl[sh * 64 + i] * __bfloat162float(vls[sh * 64 + i][v]);
                red[tid] = acc;
            }
            __syncthreads();
            if (tid < VV) {
                float cv = (red[tid] + red[tid+128] + red[tid+256] + red[tid+384]) * inv;
                cstage[tid] = __float2bfloat16(cv);
            }
            __syncthreads();
            if (tid < 16) {
                u32x4 v = *(const u32x4*)&cstage[tid * 8];
                cstore16((void*)(CTXs + (size_t)rnd * BB * VV + (size_t)b * VV + tid * 8), v);
                *(u32x4*)(AlogT + (size_t)b * KLOG + HH + tid * 8) = v;  // normal store
            }
            VMCNT0;
            if (tid == 0) cstore4i(&flagc[bid], rnd);
        }
        if (w == 0) poll32(flagc, rnd, l);
        __syncthreads();
    }
}

// ---------------- deferred logits GEMM ----------------
__global__ __launch_bounds__(256) void logits_gemm(
    const __hip_bfloat16* __restrict__ Alog,
    const __hip_bfloat16* __restrict__ W,
    const float* __restrict__ bout,
    float* __restrict__ out)
{
    int n0 = blockIdx.x * 128;
    int m0 = blockIdx.y * 128;
    int wv = threadIdx.x >> 6, l = threadIdx.x & 63;
    int l15 = l & 15, l4 = l >> 4;

    f32x4 acc[8][2] = {};
    const __hip_bfloat16* Ap = Alog + (size_t)(m0 + l15) * KLOG + l4 * 8;
    const __hip_bfloat16* Bp = W    + (size_t)(n0 + wv * 32 + l15) * KLOG + l4 * 8;

    for (int kt = 0; kt < KLOG; kt += 32) {
        bf16x8 b0 = *(const bf16x8*)(Bp + kt);
        bf16x8 b1 = *(const bf16x8*)(Bp + (size_t)16 * KLOG + kt);
        #pragma unroll
        for (int ms = 0; ms < 8; ++ms) {
            bf16x8 a = *(const bf16x8*)(Ap + (size_t)ms * 16 * KLOG + kt);
            acc[ms][0] = MFMA(a, b0, acc[ms][0]);
            acc[ms][1] = MFMA(a, b1, acc[ms][1]);
        }
    }
    #pragma unroll
    for (int ms = 0; ms < 8; ++ms)
        #pragma unroll
        for (int ns = 0; ns < 2; ++ns) {
            int col = n0 + wv * 32 + ns * 16 + l15;
            if (col < VOC) {
                float bias = bout[col];
                #pragma unroll
                for (int r = 0; r < 4; ++r) {
                    int m = m0 + ms * 16 + l4 * 4 + r;
                    int b = m & 31, t = m >> 5;
                    out[((size_t)b * TT + t) * VOC + col] = acc[ms][ns][r] + bias;
                }
            }
        }
}

// ---------------- host ----------------
extern "C" void kernel_launch(void* const* d_in, const int* in_sizes, int n_in,
                              void* d_out, int out_size, void* d_ws, size_t ws_size,
                              hipStream_t stream)
{
    (void)in_sizes; (void)n_in; (void)out_size; (void)ws_size;
    const int*   dec  = (const int*)  d_in[0];
    const float* enc  = (const float*)d_in[2];
    const float* keys = (const float*)d_in[3];
    const float* vals = (const float*)d_in[4];
    const float* emb  = (const float*)d_in[5];
    const float* Wih1 = (const float*)d_in[6];
    const float* Whh1 = (const float*)d_in[7];
    const float* b1   = (const float*)d_in[8];
    const float* Wih2 = (const float*)d_in[9];
    const float* Whh2 = (const float*)d_in[10];
    const float* b2   = (const float*)d_in[11];
    const float* Wq   = (const float*)d_in[12];
    const float* bq   = (const float*)d_in[13];
    const float* Wout = (const float*)d_in[14];
    const float* bout = (const float*)d_in[15];
    float* out = (float*)d_out;

    // workspace carve (~70 MB)
    char* p = (char*)d_ws;
    __hip_bfloat16* WoutP = (__hip_bfloat16*)p; p += (size_t)VOCP * KLOG * 2;          // 18.6 MB
    __hip_bfloat16* Alog  = (__hip_bfloat16*)p; p += (size_t)TT * BB * KLOG * 2;       // 9.4 MB
    __hip_bfloat16* Aemb  = (__hip_bfloat16*)p; p += (size_t)TT * BB * EE * 2;         // 4.2 MB
    __hip_bfloat16* H1s   = (__hip_bfloat16*)p; p += (size_t)(TT + 1) * BB * HH * 2;   // 8.45 MB
    __hip_bfloat16* H2s   = (__hip_bfloat16*)p; p += (size_t)(TT + 1) * BB * HH * 2;   // 8.45 MB
    __hip_bfloat16* CTXs  = (__hip_bfloat16*)p; p += (size_t)(TT + 1) * BB * VV * 2;   // 1.06 MB
    float* h2fs = (float*)p; p += (size_t)(TT + 1) * BB * HH * 4;                      // 16.9 MB
    float* q_s  = (float*)p; p += (size_t)(TT + 1) * BB * KK * 4;                      // 2.1 MB
    int* bar = (int*)p; p += 4096;

    pack_wout  <<<dim3((KLOG + 255) / 256, VOCP), 256, 0, stream>>>(Wout, WoutP);
    init_state <<<dim3(128), 256, 0, stream>>>(enc, H1s, H2s, bar);
    gather_emb <<<dim3(TT * BB), 256, 0, stream>>>(dec, emb, Aemb);

    decoder_persistent<<<dim3(NB2), 512, KK * SS * 2 + SS * VV * 2, stream>>>(
        Wih1, Whh1, b1, Wih2, Whh2, b2, Wq, bq, keys, vals,
        Aemb, H1s, H2s, CTXs, h2fs, q_s, Alog, bar);

    logits_gemm<<<dim3(VOCP / 128, (BB * TT) / 128), 256, 0, stream>>>(Alog, WoutP, bout, out);
}